// Round 8
// baseline (873.080 us; speedup 1.0000x reference)
//
#include <hip/hip_runtime.h>
#include <hip/hip_bf16.h>

#define NN 50000
#define NE 800000
#define FIN 128
#define HC 256
#define NEG_SLOPE 0.2f

typedef short bf16x8 __attribute__((ext_vector_type(8)));
typedef float f32x4 __attribute__((ext_vector_type(4)));

__device__ __forceinline__ unsigned short f2bf(float f) {
  unsigned u = __float_as_uint(f);
  u += 0x7fff + ((u >> 16) & 1);  // RTN-even
  return (unsigned short)(u >> 16);
}
__device__ __forceinline__ float bf2f(unsigned short s) {
  return __uint_as_float((unsigned)s << 16);
}
__device__ __forceinline__ float bflo(unsigned u) { return __uint_as_float(u << 16); }
__device__ __forceinline__ float bfhi(unsigned u) { return __uint_as_float(u & 0xffff0000u); }

// ---------------- input conversion: fp32 -> bf16 (A side needs no residual now) ------
__global__ __launch_bounds__(256) void convert_x(const float* __restrict__ X,
                                                 unsigned short* __restrict__ Xh,
                                                 int n4) {
  int i = blockIdx.x * 256 + threadIdx.x;
  if (i >= n4) return;
  float4 v = ((const float4*)X)[i];
  ushort4 h;
  h.x = f2bf(v.x);
  h.y = f2bf(v.y);
  h.z = f2bf(v.z);
  h.w = f2bf(v.w);
  ((ushort4*)Xh)[i] = h;
}

// W [K][HC] fp32 -> Wt hi/lo [HC][K] bf16 (transpose + split; weights keep residual)
__global__ __launch_bounds__(256) void convert_w(const float* __restrict__ W,
                                                 unsigned short* __restrict__ Wth,
                                                 unsigned short* __restrict__ Wtl,
                                                 int K) {
  int i = blockIdx.x * 256 + threadIdx.x;
  if (i >= K * HC) return;
  int k = i / HC, n = i % HC;
  float v = W[i];
  unsigned short h = f2bf(v);
  Wth[n * K + k] = h;
  Wtl[n * K + k] = f2bf(v - bf2f(h));
}

// ---------------- MFMA GEMM + fused attention coefficients ----------------
// Cb(bf16)[M,256] = A_bf16 @ (Bh+Bl)^T (stored [N][K]); 2-term split.
// Epilogue also computes a_s[n,h] = <C_row, att_src> and a_d likewise, per-head.
// Heads are 32-col groups; a 128-col block owns its 4 heads completely.
__global__ __launch_bounds__(256) void gemm_coef(
    const unsigned short* __restrict__ A, const unsigned short* __restrict__ Bth,
    const unsigned short* __restrict__ Btl, const float* __restrict__ att_s,
    const float* __restrict__ att_d, unsigned short* __restrict__ Cb,
    float* __restrict__ a_s, float* __restrict__ a_d, int M, int K) {
  __shared__ unsigned short sA[128 * 40];   // stride 40 shorts: <=2-way banks (free)
  __shared__ unsigned short sBh[128 * 40];
  __shared__ unsigned short sBl[128 * 40];
  __shared__ float sAS[128][4];
  __shared__ float sAD[128][4];

  int t = threadIdx.x;
  int w = t >> 6, lane = t & 63;
  int quad = lane >> 4, lrow = lane & 15;
  int m0 = blockIdx.x * 128, n0 = blockIdx.y * 128;
  int wm = (w >> 1) * 64, wn = (w & 1) * 64;

  if (t < 128) {
#pragma unroll
    for (int j = 0; j < 4; ++j) { sAS[t][j] = 0.f; sAD[t][j] = 0.f; }
  }
  // (ordered vs later atomics by the k-loop's __syncthreads)

  f32x4 acc[4][4] = {};

  for (int k0 = 0; k0 < K; k0 += 32) {
#pragma unroll
    for (int i = 0; i < 2; ++i) {
      int idx = t + i * 256;           // 0..511
      int row = idx >> 2, q = idx & 3;
      int gm = m0 + row;
      if (gm >= M) gm = M - 1;
      size_t ga = (size_t)gm * K + k0 + q * 8;
      size_t gb = (size_t)(n0 + row) * K + k0 + q * 8;
      *(uint4*)(sA + row * 40 + q * 8) = *(const uint4*)(A + ga);
      *(uint4*)(sBh + row * 40 + q * 8) = *(const uint4*)(Bth + gb);
      *(uint4*)(sBl + row * 40 + q * 8) = *(const uint4*)(Btl + gb);
    }
    __syncthreads();

    bf16x8 fa[4];
#pragma unroll
    for (int mi = 0; mi < 4; ++mi)
      fa[mi] = *(const bf16x8*)(sA + (wm + mi * 16 + lrow) * 40 + quad * 8);
#pragma unroll
    for (int ni = 0; ni < 4; ++ni) {
      bf16x8 fbh = *(const bf16x8*)(sBh + (wn + ni * 16 + lrow) * 40 + quad * 8);
      bf16x8 fbl = *(const bf16x8*)(sBl + (wn + ni * 16 + lrow) * 40 + quad * 8);
#pragma unroll
      for (int mi = 0; mi < 4; ++mi) {
        acc[mi][ni] = __builtin_amdgcn_mfma_f32_16x16x32_bf16(fa[mi], fbh, acc[mi][ni], 0, 0, 0);
        acc[mi][ni] = __builtin_amdgcn_mfma_f32_16x16x32_bf16(fa[mi], fbl, acc[mi][ni], 0, 0, 0);
      }
    }
    __syncthreads();
  }

  // C/D layout: col = lane&15, row = quad*4 + reg  [m89-verified]
#pragma unroll
  for (int mi = 0; mi < 4; ++mi) {
#pragma unroll
    for (int r = 0; r < 4; ++r) {
      int lr = wm + mi * 16 + quad * 4 + r;  // local row
      int gm = m0 + lr;
      if (gm < M) {
#pragma unroll
        for (int ni = 0; ni < 4; ++ni) {
          int lc = wn + ni * 16 + lrow;      // local col
          int gn = n0 + lc;
          float v = acc[mi][ni][r];
          Cb[(size_t)gm * HC + gn] = f2bf(v);
          int hd = lc >> 5;
          atomicAdd(&sAS[lr][hd], v * att_s[gn]);
          atomicAdd(&sAD[lr][hd], v * att_d[gn]);
        }
      }
    }
  }
  __syncthreads();
  if (t < 128) {
    int gm = m0 + t;
    if (gm < M) {
      int hb = n0 >> 5;  // first head covered by this col-block (0 or 4)
#pragma unroll
      for (int j = 0; j < 4; ++j) {
        a_s[gm * 8 + hb + j] = sAS[t][j];
        a_d[gm * 8 + hb + j] = sAD[t][j];
      }
    }
  }
}

// ---------------- CSR build (dst-major); counts memset to 0, +1 applied in scan1 -----
__global__ void hist_kernel(const int* __restrict__ ei, int* __restrict__ counts) {
  int e = blockIdx.x * 256 + threadIdx.x;
  if (e < NE) atomicAdd(&counts[ei[NE + e]], 1);
}

__global__ void scan1(const int* __restrict__ counts, int* __restrict__ scanbuf,
                      int* __restrict__ bsum) {
  __shared__ int sd[256];
  int t = threadIdx.x;
  int i = blockIdx.x * 256 + t;
  int v = (i < NN) ? counts[i] + 1 : 0;  // +1 = self-loop
  sd[t] = v;
  __syncthreads();
#pragma unroll
  for (int off = 1; off < 256; off <<= 1) {
    int x = (t >= off) ? sd[t - off] : 0;
    __syncthreads();
    sd[t] += x;
    __syncthreads();
  }
  if (i < NN) scanbuf[i] = sd[t];
  if (t == 255) bsum[blockIdx.x] = sd[255];
}

__global__ void scan2(const int* __restrict__ bsum, int* __restrict__ boff, int nb) {
  __shared__ int sd[256];
  int t = threadIdx.x;
  int v = (t < nb) ? bsum[t] : 0;
  sd[t] = v;
  __syncthreads();
#pragma unroll
  for (int off = 1; off < 256; off <<= 1) {
    int x = (t >= off) ? sd[t - off] : 0;
    __syncthreads();
    sd[t] += x;
    __syncthreads();
  }
  if (t < nb) boff[t] = sd[t] - v;  // exclusive
}

__global__ void scan3(const int* __restrict__ scanbuf, const int* __restrict__ boff,
                      int* __restrict__ rowptr) {
  int i = blockIdx.x * 256 + threadIdx.x;
  if (i < NN) rowptr[i + 1] = scanbuf[i] + boff[blockIdx.x];
  if (i == 0) rowptr[0] = 0;
}

__global__ void scatter_kernel(const int* __restrict__ ei, const int* __restrict__ rowptr,
                               int* __restrict__ tmp, int* __restrict__ col,
                               int* __restrict__ eidv) {
  int e = blockIdx.x * 256 + threadIdx.x;
  if (e >= NE + NN) return;
  int s, d, id;
  if (e < NE) { s = ei[e]; d = ei[NE + e]; id = e; }
  else { s = d = e - NE; id = -1; }
  int pos = rowptr[d] + atomicAdd(&tmp[d], 1);
  col[pos] = s;
  eidv[pos] = id;
}

// ---------------- aggregation: 32 lanes per dst (2 dst/wave), masked 4-edge unroll ----
// lane l owns channels [8l, 8l+8) -> one uint4 per gathered row. No-max softmax
// (logits bounded; alpha identical to reference). Optional fused node_pred.
__global__ __launch_bounds__(256) void agg_kernel(
    const unsigned short* __restrict__ htb, const float* __restrict__ a_s,
    const float* __restrict__ a_d, const int* __restrict__ rowptr,
    const int* __restrict__ col, const float* __restrict__ bias,
    unsigned short* __restrict__ outb,
    const float* __restrict__ Wn, const float* __restrict__ bn,
    float* __restrict__ outn) {
  int d = blockIdx.x * 8 + (threadIdx.x >> 5);
  if (d >= NN) return;
  int l = threadIdx.x & 31;
  int hh = l >> 2;
  float adh = a_d[d * 8 + hh];
  int r0 = rowptr[d], r1 = rowptr[d + 1];
  float denom = 0.f;
  float4 acc0 = {0.f, 0.f, 0.f, 0.f};
  float4 acc1 = {0.f, 0.f, 0.f, 0.f};
  for (int r = r0; r < r1; r += 4) {
    int s[4];
    float as_[4];
    uint4 q[4];
    bool ok[4];
#pragma unroll
    for (int j = 0; j < 4; ++j) {
      int rj = r + j;
      ok[j] = rj < r1;
      rj = ok[j] ? rj : r1 - 1;  // clamp: duplicate load, weight zeroed
      s[j] = col[rj];
    }
#pragma unroll
    for (int j = 0; j < 4; ++j) {
      as_[j] = a_s[s[j] * 8 + hh];
      q[j] = ((const uint4*)(htb + (size_t)s[j] * HC))[l];
    }
#pragma unroll
    for (int j = 0; j < 4; ++j) {
      float e = as_[j] + adh;
      e = e > 0.f ? e : NEG_SLOPE * e;
      float w = ok[j] ? __expf(e) : 0.f;
      denom += w;
      acc0.x += w * bflo(q[j].x);
      acc0.y += w * bfhi(q[j].x);
      acc0.z += w * bflo(q[j].y);
      acc0.w += w * bfhi(q[j].y);
      acc1.x += w * bflo(q[j].z);
      acc1.y += w * bfhi(q[j].z);
      acc1.z += w * bflo(q[j].w);
      acc1.w += w * bfhi(q[j].w);
    }
  }
  float dv = 1.f / denom;  // denom >= 1 (self-loop)
  float4 b0 = *(const float4*)(bias + l * 8);
  float4 b1 = *(const float4*)(bias + l * 8 + 4);
  float4 o0, o1;
  o0.x = fmaxf(fmaf(acc0.x, dv, b0.x), 0.f);
  o0.y = fmaxf(fmaf(acc0.y, dv, b0.y), 0.f);
  o0.z = fmaxf(fmaf(acc0.z, dv, b0.z), 0.f);
  o0.w = fmaxf(fmaf(acc0.w, dv, b0.w), 0.f);
  o1.x = fmaxf(fmaf(acc1.x, dv, b1.x), 0.f);
  o1.y = fmaxf(fmaf(acc1.y, dv, b1.y), 0.f);
  o1.z = fmaxf(fmaf(acc1.z, dv, b1.z), 0.f);
  o1.w = fmaxf(fmaf(acc1.w, dv, b1.w), 0.f);
  uint4 pb;
  pb.x = (unsigned)f2bf(o0.x) | ((unsigned)f2bf(o0.y) << 16);
  pb.y = (unsigned)f2bf(o0.z) | ((unsigned)f2bf(o0.w) << 16);
  pb.z = (unsigned)f2bf(o1.x) | ((unsigned)f2bf(o1.y) << 16);
  pb.w = (unsigned)f2bf(o1.z) | ((unsigned)f2bf(o1.w) << 16);
  ((uint4*)(outb + (size_t)d * HC))[l] = pb;
  if (outn) {
    const float4* wnp = (const float4*)(Wn + l * 8);
    float4 w0 = wnp[0], w1 = wnp[1];
    float p = o0.x * w0.x + o0.y * w0.y + o0.z * w0.z + o0.w * w0.w +
              o1.x * w1.x + o1.y * w1.y + o1.z * w1.z + o1.w * w1.w;
#pragma unroll
    for (int off = 1; off <= 16; off <<= 1) p += __shfl_xor(p, off);
    if (l == 0) outn[d] = p + bn[0];
  }
}

// ---------------- edge predictions: 16-lane group per edge, 2-edge unroll ----------------
__global__ __launch_bounds__(256) void edge_pred_kernel(
    const unsigned short* __restrict__ h2b, const int* __restrict__ rowptr,
    const int* __restrict__ col, const int* __restrict__ eidv,
    const float* __restrict__ We, const float* __restrict__ be,
    float* __restrict__ out) {
  int d = blockIdx.x * 4 + (threadIdx.x >> 6);
  if (d >= NN) return;
  int lane = threadIdx.x & 63;
  int g = lane >> 4, l = lane & 15;
  float b = be[0];

  const uint4* rowd = (const uint4*)(h2b + (size_t)d * HC + l * 16);
  uint4 qd0 = rowd[0], qd1 = rowd[1];
  float wd[16];
  {
    const float4* wep = (const float4*)(We + l * 16);
    float4 w0 = wep[0], w1 = wep[1], w2 = wep[2], w3 = wep[3];
    wd[0] = bflo(qd0.x) * w0.x;  wd[1] = bfhi(qd0.x) * w0.y;
    wd[2] = bflo(qd0.y) * w0.z;  wd[3] = bfhi(qd0.y) * w0.w;
    wd[4] = bflo(qd0.z) * w1.x;  wd[5] = bfhi(qd0.z) * w1.y;
    wd[6] = bflo(qd0.w) * w1.z;  wd[7] = bfhi(qd0.w) * w1.w;
    wd[8] = bflo(qd1.x) * w2.x;  wd[9] = bfhi(qd1.x) * w2.y;
    wd[10] = bflo(qd1.y) * w2.z; wd[11] = bfhi(qd1.y) * w2.w;
    wd[12] = bflo(qd1.z) * w3.x; wd[13] = bfhi(qd1.z) * w3.y;
    wd[14] = bflo(qd1.w) * w3.z; wd[15] = bfhi(qd1.w) * w3.w;
  }

  int r0 = rowptr[d], r1 = rowptr[d + 1];
  for (int r = r0; r < r1; r += 8) {
    int rr0 = r + g, rr1 = r + 4 + g;
    int s0 = 0, id0 = -1, s1 = 0, id1 = -1;
    if (rr0 < r1) { s0 = col[rr0]; id0 = eidv[rr0]; }
    if (rr1 < r1) { s1 = col[rr1]; id1 = eidv[rr1]; }
    const uint4* ra = (const uint4*)(h2b + (size_t)s0 * HC + l * 16);
    const uint4* rb = (const uint4*)(h2b + (size_t)s1 * HC + l * 16);
    uint4 a0 = ra[0], a1 = ra[1];
    uint4 c0 = rb[0], c1 = rb[1];
    float p0 = bflo(a0.x) * wd[0] + bfhi(a0.x) * wd[1] + bflo(a0.y) * wd[2] +
               bfhi(a0.y) * wd[3] + bflo(a0.z) * wd[4] + bfhi(a0.z) * wd[5] +
               bflo(a0.w) * wd[6] + bfhi(a0.w) * wd[7] + bflo(a1.x) * wd[8] +
               bfhi(a1.x) * wd[9] + bflo(a1.y) * wd[10] + bfhi(a1.y) * wd[11] +
               bflo(a1.z) * wd[12] + bfhi(a1.z) * wd[13] + bflo(a1.w) * wd[14] +
               bfhi(a1.w) * wd[15];
    float p1 = bflo(c0.x) * wd[0] + bfhi(c0.x) * wd[1] + bflo(c0.y) * wd[2] +
               bfhi(c0.y) * wd[3] + bflo(c0.z) * wd[4] + bfhi(c0.z) * wd[5] +
               bflo(c0.w) * wd[6] + bfhi(c0.w) * wd[7] + bflo(c1.x) * wd[8] +
               bfhi(c1.x) * wd[9] + bflo(c1.y) * wd[10] + bfhi(c1.y) * wd[11] +
               bflo(c1.z) * wd[12] + bfhi(c1.z) * wd[13] + bflo(c1.w) * wd[14] +
               bfhi(c1.w) * wd[15];
#pragma unroll
    for (int off = 1; off <= 8; off <<= 1) {
      p0 += __shfl_xor(p0, off);
      p1 += __shfl_xor(p1, off);
    }
    if (l == 0) {
      if (id0 >= 0) out[id0] = p0 + b;
      if (id1 >= 0) out[id1] = p1 + b;
    }
  }
}

extern "C" void kernel_launch(void* const* d_in, const int* in_sizes, int n_in,
                              void* d_out, int out_size, void* d_ws, size_t ws_size,
                              hipStream_t stream) {
  const float* x  = (const float*)d_in[0];
  const int* ei   = (const int*)d_in[1];
  const float* W1 = (const float*)d_in[3];
  const float* as1 = (const float*)d_in[4];
  const float* ad1 = (const float*)d_in[5];
  const float* b1 = (const float*)d_in[6];
  const float* W2 = (const float*)d_in[7];
  const float* as2 = (const float*)d_in[8];
  const float* ad2 = (const float*)d_in[9];
  const float* b2 = (const float*)d_in[10];
  const float* We = (const float*)d_in[11];
  const float* be = (const float*)d_in[12];
  const float* Wn = (const float*)d_in[13];
  const float* bn = (const float*)d_in[14];
  float* out = (float*)d_out;

  char* wsp = (char*)d_ws;
  auto alloc = [&](size_t bytes) {
    char* p = wsp;
    wsp += (bytes + 255) & ~(size_t)255;
    return p;
  };
  unsigned short* hbA = (unsigned short*)alloc((size_t)NN * HC * 2); // gemm out bf16 (both layers)
  unsigned short* h1b = (unsigned short*)alloc((size_t)NN * HC * 2); // agg1 out bf16 (xh aliases)
  unsigned short* hbB = (unsigned short*)alloc((size_t)NN * HC * 2); // agg2 out bf16
  float* a_s = (float*)alloc((size_t)NN * 8 * 4);
  float* a_d = (float*)alloc((size_t)NN * 8 * 4);
  int* rowptr = (int*)alloc((size_t)(NN + 1) * 4);
  int* colv = (int*)alloc((size_t)(NE + NN + 8) * 4);
  int* eidv = (int*)alloc((size_t)(NE + NN + 8) * 4);
  int* counts = (int*)alloc((size_t)NN * 4);   // reused for W1t after CSR build
  int* tmp = (int*)alloc((size_t)NN * 4);      // reused for W2th after CSR build
  int* scanbuf = (int*)alloc((size_t)NN * 4);  // reused for W2tl after CSR build
  int* bsum = (int*)alloc(256 * 4);
  int* boff = (int*)alloc(256 * 4);

  // aliases (lifetimes disjoint):
  unsigned short* xh = h1b;  // x bf16 dead once gemm1 consumed it; agg1 then writes h1b
  unsigned short* W1th = (unsigned short*)counts;
  unsigned short* W1tl = (unsigned short*)counts + FIN * HC;
  unsigned short* W2th = (unsigned short*)tmp;
  unsigned short* W2tl = (unsigned short*)scanbuf;

  const int NB = (NN + 255) / 256;

  // CSR build (counts/tmp zeroed by memset; self-loop +1 folded into scan1)
  hipMemsetAsync(counts, 0, (size_t)NN * 4, stream);
  hipMemsetAsync(tmp, 0, (size_t)NN * 4, stream);
  hist_kernel<<<(NE + 255) / 256, 256, 0, stream>>>(ei, counts);
  scan1<<<NB, 256, 0, stream>>>(counts, scanbuf, bsum);
  scan2<<<1, 256, 0, stream>>>(bsum, boff, NB);
  scan3<<<NB, 256, 0, stream>>>(scanbuf, boff, rowptr);
  scatter_kernel<<<(NE + NN + 255) / 256, 256, 0, stream>>>(ei, rowptr, tmp, colv, eidv);

  // conversions (after CSR build so the scratch overlay is safe)
  convert_x<<<(NN * FIN / 4 + 255) / 256, 256, 0, stream>>>(x, xh, NN * FIN / 4);
  convert_w<<<(FIN * HC + 255) / 256, 256, 0, stream>>>(W1, W1th, W1tl, FIN);
  convert_w<<<(HC * HC + 255) / 256, 256, 0, stream>>>(W2, W2th, W2tl, HC);

  dim3 ggrid((NN + 127) / 128, 2);

  // layer 1 (coef fused into gemm epilogue)
  gemm_coef<<<ggrid, 256, 0, stream>>>(xh, W1th, W1tl, as1, ad1, hbA, a_s, a_d, NN, FIN);
  agg_kernel<<<NN / 8, 256, 0, stream>>>(hbA, a_s, a_d, rowptr, colv, b1, h1b,
                                         (const float*)nullptr, (const float*)nullptr,
                                         (float*)nullptr);

  // layer 2 (coef fused; node_pred fused into agg epilogue)
  gemm_coef<<<ggrid, 256, 0, stream>>>(h1b, W2th, W2tl, as2, ad2, hbA, a_s, a_d, NN, HC);
  agg_kernel<<<NN / 8, 256, 0, stream>>>(hbA, a_s, a_d, rowptr, colv, b2, hbB,
                                         Wn, bn, out + NE);

  // edge predictions
  edge_pred_kernel<<<NN / 4, 256, 0, stream>>>(hbB, rowptr, colv, eidv, We, be, out);
}

// Round 9
// 469.794 us; speedup vs baseline: 1.8584x; 1.8584x over previous
//
#include <hip/hip_runtime.h>
#include <hip/hip_bf16.h>

#define NN 50000
#define NE 800000
#define FIN 128
#define HC 256
#define NEG_SLOPE 0.2f

typedef short bf16x8 __attribute__((ext_vector_type(8)));
typedef float f32x4 __attribute__((ext_vector_type(4)));

__device__ __forceinline__ unsigned short f2bf(float f) {
  unsigned u = __float_as_uint(f);
  u += 0x7fff + ((u >> 16) & 1);  // RTN-even
  return (unsigned short)(u >> 16);
}
__device__ __forceinline__ float bf2f(unsigned short s) {
  return __uint_as_float((unsigned)s << 16);
}
__device__ __forceinline__ float bflo(unsigned u) { return __uint_as_float(u << 16); }
__device__ __forceinline__ float bfhi(unsigned u) { return __uint_as_float(u & 0xffff0000u); }

// ---------------- input conversion: fp32 -> bf16 (A side, no residual) ------
__global__ __launch_bounds__(256) void convert_x(const float* __restrict__ X,
                                                 unsigned short* __restrict__ Xh,
                                                 int n4) {
  int i = blockIdx.x * 256 + threadIdx.x;
  if (i >= n4) return;
  float4 v = ((const float4*)X)[i];
  ushort4 h;
  h.x = f2bf(v.x);
  h.y = f2bf(v.y);
  h.z = f2bf(v.z);
  h.w = f2bf(v.w);
  ((ushort4*)Xh)[i] = h;
}

// W [K][HC] fp32 -> Wt hi/lo [HC][K] bf16 (transpose + split; weights keep residual)
__global__ __launch_bounds__(256) void convert_w(const float* __restrict__ W,
                                                 unsigned short* __restrict__ Wth,
                                                 unsigned short* __restrict__ Wtl,
                                                 int K) {
  int i = blockIdx.x * 256 + threadIdx.x;
  if (i >= K * HC) return;
  int k = i / HC, n = i % HC;
  float v = W[i];
  unsigned short h = f2bf(v);
  Wth[n * K + k] = h;
  Wtl[n * K + k] = f2bf(v - bf2f(h));
}

// ---------------- MFMA GEMM + fused attention coefficients (shuffle reduce) --------
// Cb(bf16)[M,256] = A_bf16 @ (Bh+Bl)^T (stored [N][K]); 2-term split.
// Epilogue: a_s[n,h] = <C_row_head, att_src>, a_d likewise. Each wave owns complete
// head-pairs (cols [wn, wn+64) = heads hb, hb+1), rows wm..wm+63 — no overlap across
// waves/blocks, so a 16-lane shuffle reduction + one scalar store suffices (NO atomics;
// round-8's LDS atomicAdd version serialized ~8-way and was 243 us).
__global__ __launch_bounds__(256) void gemm_coef(
    const unsigned short* __restrict__ A, const unsigned short* __restrict__ Bth,
    const unsigned short* __restrict__ Btl, const float* __restrict__ att_s,
    const float* __restrict__ att_d, unsigned short* __restrict__ Cb,
    float* __restrict__ a_s, float* __restrict__ a_d, int M, int K) {
  __shared__ unsigned short sA[128 * 40];   // stride 40 shorts: <=2-way banks (free)
  __shared__ unsigned short sBh[128 * 40];
  __shared__ unsigned short sBl[128 * 40];

  int t = threadIdx.x;
  int w = t >> 6, lane = t & 63;
  int quad = lane >> 4, lrow = lane & 15;
  int m0 = blockIdx.x * 128, n0 = blockIdx.y * 128;
  int wm = (w >> 1) * 64, wn = (w & 1) * 64;

  f32x4 acc[4][4] = {};

  for (int k0 = 0; k0 < K; k0 += 32) {
#pragma unroll
    for (int i = 0; i < 2; ++i) {
      int idx = t + i * 256;           // 0..511
      int row = idx >> 2, q = idx & 3;
      int gm = m0 + row;
      if (gm >= M) gm = M - 1;
      size_t ga = (size_t)gm * K + k0 + q * 8;
      size_t gb = (size_t)(n0 + row) * K + k0 + q * 8;
      *(uint4*)(sA + row * 40 + q * 8) = *(const uint4*)(A + ga);
      *(uint4*)(sBh + row * 40 + q * 8) = *(const uint4*)(Bth + gb);
      *(uint4*)(sBl + row * 40 + q * 8) = *(const uint4*)(Btl + gb);
    }
    __syncthreads();

    bf16x8 fa[4];
#pragma unroll
    for (int mi = 0; mi < 4; ++mi)
      fa[mi] = *(const bf16x8*)(sA + (wm + mi * 16 + lrow) * 40 + quad * 8);
#pragma unroll
    for (int ni = 0; ni < 4; ++ni) {
      bf16x8 fbh = *(const bf16x8*)(sBh + (wn + ni * 16 + lrow) * 40 + quad * 8);
      bf16x8 fbl = *(const bf16x8*)(sBl + (wn + ni * 16 + lrow) * 40 + quad * 8);
#pragma unroll
      for (int mi = 0; mi < 4; ++mi) {
        acc[mi][ni] = __builtin_amdgcn_mfma_f32_16x16x32_bf16(fa[mi], fbh, acc[mi][ni], 0, 0, 0);
        acc[mi][ni] = __builtin_amdgcn_mfma_f32_16x16x32_bf16(fa[mi], fbl, acc[mi][ni], 0, 0, 0);
      }
    }
    __syncthreads();
  }

  // att values for this lane's 4 columns (hoisted)
  float vs[4], vd[4];
#pragma unroll
  for (int ni = 0; ni < 4; ++ni) {
    int gn = n0 + wn + ni * 16 + lrow;
    vs[ni] = att_s[gn];
    vd[ni] = att_d[gn];
  }
  int hb = (n0 + wn) >> 5;  // first head owned by this wave

  // C/D layout: col = lane&15, row = quad*4 + reg  [m89-verified]
#pragma unroll
  for (int mi = 0; mi < 4; ++mi) {
#pragma unroll
    for (int r = 0; r < 4; ++r) {
      int gm = m0 + wm + mi * 16 + quad * 4 + r;
      bool rowok = gm < M;
      if (rowok) {
#pragma unroll
        for (int ni = 0; ni < 4; ++ni) {
          int gn = n0 + wn + ni * 16 + lrow;
          Cb[(size_t)gm * HC + gn] = f2bf(acc[mi][ni][r]);
        }
      }
      // per-head partial dots: ni 0,1 -> head hb ; ni 2,3 -> head hb+1
      float pse = acc[mi][0][r] * vs[0] + acc[mi][1][r] * vs[1];
      float pso = acc[mi][2][r] * vs[2] + acc[mi][3][r] * vs[3];
      float pde = acc[mi][0][r] * vd[0] + acc[mi][1][r] * vd[1];
      float pdo = acc[mi][2][r] * vd[2] + acc[mi][3][r] * vd[3];
#pragma unroll
      for (int off = 1; off <= 8; off <<= 1) {
        pse += __shfl_xor(pse, off);
        pso += __shfl_xor(pso, off);
        pde += __shfl_xor(pde, off);
        pdo += __shfl_xor(pdo, off);
      }
      if (lrow == 0 && rowok) {
        a_s[gm * 8 + hb] = pse;
        a_s[gm * 8 + hb + 1] = pso;
        a_d[gm * 8 + hb] = pde;
        a_d[gm * 8 + hb + 1] = pdo;
      }
    }
  }
}

// ---------------- CSR build (dst-major); counts memset to 0, +1 applied in scan1 -----
__global__ void hist_kernel(const int* __restrict__ ei, int* __restrict__ counts) {
  int e = blockIdx.x * 256 + threadIdx.x;
  if (e < NE) atomicAdd(&counts[ei[NE + e]], 1);
}

__global__ void scan1(const int* __restrict__ counts, int* __restrict__ scanbuf,
                      int* __restrict__ bsum) {
  __shared__ int sd[256];
  int t = threadIdx.x;
  int i = blockIdx.x * 256 + t;
  int v = (i < NN) ? counts[i] + 1 : 0;  // +1 = self-loop
  sd[t] = v;
  __syncthreads();
#pragma unroll
  for (int off = 1; off < 256; off <<= 1) {
    int x = (t >= off) ? sd[t - off] : 0;
    __syncthreads();
    sd[t] += x;
    __syncthreads();
  }
  if (i < NN) scanbuf[i] = sd[t];
  if (t == 255) bsum[blockIdx.x] = sd[255];
}

__global__ void scan2(const int* __restrict__ bsum, int* __restrict__ boff, int nb) {
  __shared__ int sd[256];
  int t = threadIdx.x;
  int v = (t < nb) ? bsum[t] : 0;
  sd[t] = v;
  __syncthreads();
#pragma unroll
  for (int off = 1; off < 256; off <<= 1) {
    int x = (t >= off) ? sd[t - off] : 0;
    __syncthreads();
    sd[t] += x;
    __syncthreads();
  }
  if (t < nb) boff[t] = sd[t] - v;  // exclusive
}

__global__ void scan3(const int* __restrict__ scanbuf, const int* __restrict__ boff,
                      int* __restrict__ rowptr) {
  int i = blockIdx.x * 256 + threadIdx.x;
  if (i < NN) rowptr[i + 1] = scanbuf[i] + boff[blockIdx.x];
  if (i == 0) rowptr[0] = 0;
}

__global__ void scatter_kernel(const int* __restrict__ ei, const int* __restrict__ rowptr,
                               int* __restrict__ tmp, int* __restrict__ col,
                               int* __restrict__ eidv) {
  int e = blockIdx.x * 256 + threadIdx.x;
  if (e >= NE + NN) return;
  int s, d, id;
  if (e < NE) { s = ei[e]; d = ei[NE + e]; id = e; }
  else { s = d = e - NE; id = -1; }
  int pos = rowptr[d] + atomicAdd(&tmp[d], 1);
  col[pos] = s;
  eidv[pos] = id;
}

// ---------------- aggregation: 32 lanes per dst (2 dst/wave), masked 4-edge unroll ----
// lane l owns channels [8l, 8l+8) -> one uint4 per gathered row. No-max softmax
// (logits bounded; alpha identical to reference). Optional fused node_pred.
__global__ __launch_bounds__(256) void agg_kernel(
    const unsigned short* __restrict__ htb, const float* __restrict__ a_s,
    const float* __restrict__ a_d, const int* __restrict__ rowptr,
    const int* __restrict__ col, const float* __restrict__ bias,
    unsigned short* __restrict__ outb,
    const float* __restrict__ Wn, const float* __restrict__ bn,
    float* __restrict__ outn) {
  int d = blockIdx.x * 8 + (threadIdx.x >> 5);
  if (d >= NN) return;
  int l = threadIdx.x & 31;
  int hh = l >> 2;
  float adh = a_d[d * 8 + hh];
  int r0 = rowptr[d], r1 = rowptr[d + 1];
  float denom = 0.f;
  float4 acc0 = {0.f, 0.f, 0.f, 0.f};
  float4 acc1 = {0.f, 0.f, 0.f, 0.f};
  for (int r = r0; r < r1; r += 4) {
    int s[4];
    float as_[4];
    uint4 q[4];
    bool ok[4];
#pragma unroll
    for (int j = 0; j < 4; ++j) {
      int rj = r + j;
      ok[j] = rj < r1;
      rj = ok[j] ? rj : r1 - 1;  // clamp: duplicate load, weight zeroed
      s[j] = col[rj];
    }
#pragma unroll
    for (int j = 0; j < 4; ++j) {
      as_[j] = a_s[s[j] * 8 + hh];
      q[j] = ((const uint4*)(htb + (size_t)s[j] * HC))[l];
    }
#pragma unroll
    for (int j = 0; j < 4; ++j) {
      float e = as_[j] + adh;
      e = e > 0.f ? e : NEG_SLOPE * e;
      float w = ok[j] ? __expf(e) : 0.f;
      denom += w;
      acc0.x += w * bflo(q[j].x);
      acc0.y += w * bfhi(q[j].x);
      acc0.z += w * bflo(q[j].y);
      acc0.w += w * bfhi(q[j].y);
      acc1.x += w * bflo(q[j].z);
      acc1.y += w * bfhi(q[j].z);
      acc1.z += w * bflo(q[j].w);
      acc1.w += w * bfhi(q[j].w);
    }
  }
  float dv = 1.f / denom;  // denom >= 1 (self-loop)
  float4 b0 = *(const float4*)(bias + l * 8);
  float4 b1 = *(const float4*)(bias + l * 8 + 4);
  float4 o0, o1;
  o0.x = fmaxf(fmaf(acc0.x, dv, b0.x), 0.f);
  o0.y = fmaxf(fmaf(acc0.y, dv, b0.y), 0.f);
  o0.z = fmaxf(fmaf(acc0.z, dv, b0.z), 0.f);
  o0.w = fmaxf(fmaf(acc0.w, dv, b0.w), 0.f);
  o1.x = fmaxf(fmaf(acc1.x, dv, b1.x), 0.f);
  o1.y = fmaxf(fmaf(acc1.y, dv, b1.y), 0.f);
  o1.z = fmaxf(fmaf(acc1.z, dv, b1.z), 0.f);
  o1.w = fmaxf(fmaf(acc1.w, dv, b1.w), 0.f);
  uint4 pb;
  pb.x = (unsigned)f2bf(o0.x) | ((unsigned)f2bf(o0.y) << 16);
  pb.y = (unsigned)f2bf(o0.z) | ((unsigned)f2bf(o0.w) << 16);
  pb.z = (unsigned)f2bf(o1.x) | ((unsigned)f2bf(o1.y) << 16);
  pb.w = (unsigned)f2bf(o1.z) | ((unsigned)f2bf(o1.w) << 16);
  ((uint4*)(outb + (size_t)d * HC))[l] = pb;
  if (outn) {
    const float4* wnp = (const float4*)(Wn + l * 8);
    float4 w0 = wnp[0], w1 = wnp[1];
    float p = o0.x * w0.x + o0.y * w0.y + o0.z * w0.z + o0.w * w0.w +
              o1.x * w1.x + o1.y * w1.y + o1.z * w1.z + o1.w * w1.w;
#pragma unroll
    for (int off = 1; off <= 16; off <<= 1) p += __shfl_xor(p, off);
    if (l == 0) outn[d] = p + bn[0];
  }
}

// ---------------- edge predictions: 16-lane group per edge, 2-edge unroll ----------------
__global__ __launch_bounds__(256) void edge_pred_kernel(
    const unsigned short* __restrict__ h2b, const int* __restrict__ rowptr,
    const int* __restrict__ col, const int* __restrict__ eidv,
    const float* __restrict__ We, const float* __restrict__ be,
    float* __restrict__ out) {
  int d = blockIdx.x * 4 + (threadIdx.x >> 6);
  if (d >= NN) return;
  int lane = threadIdx.x & 63;
  int g = lane >> 4, l = lane & 15;
  float b = be[0];

  const uint4* rowd = (const uint4*)(h2b + (size_t)d * HC + l * 16);
  uint4 qd0 = rowd[0], qd1 = rowd[1];
  float wd[16];
  {
    const float4* wep = (const float4*)(We + l * 16);
    float4 w0 = wep[0], w1 = wep[1], w2 = wep[2], w3 = wep[3];
    wd[0] = bflo(qd0.x) * w0.x;  wd[1] = bfhi(qd0.x) * w0.y;
    wd[2] = bflo(qd0.y) * w0.z;  wd[3] = bfhi(qd0.y) * w0.w;
    wd[4] = bflo(qd0.z) * w1.x;  wd[5] = bfhi(qd0.z) * w1.y;
    wd[6] = bflo(qd0.w) * w1.z;  wd[7] = bfhi(qd0.w) * w1.w;
    wd[8] = bflo(qd1.x) * w2.x;  wd[9] = bfhi(qd1.x) * w2.y;
    wd[10] = bflo(qd1.y) * w2.z; wd[11] = bfhi(qd1.y) * w2.w;
    wd[12] = bflo(qd1.z) * w3.x; wd[13] = bfhi(qd1.z) * w3.y;
    wd[14] = bflo(qd1.w) * w3.z; wd[15] = bfhi(qd1.w) * w3.w;
  }

  int r0 = rowptr[d], r1 = rowptr[d + 1];
  for (int r = r0; r < r1; r += 8) {
    int rr0 = r + g, rr1 = r + 4 + g;
    int s0 = 0, id0 = -1, s1 = 0, id1 = -1;
    if (rr0 < r1) { s0 = col[rr0]; id0 = eidv[rr0]; }
    if (rr1 < r1) { s1 = col[rr1]; id1 = eidv[rr1]; }
    const uint4* ra = (const uint4*)(h2b + (size_t)s0 * HC + l * 16);
    const uint4* rb = (const uint4*)(h2b + (size_t)s1 * HC + l * 16);
    uint4 a0 = ra[0], a1 = ra[1];
    uint4 c0 = rb[0], c1 = rb[1];
    float p0 = bflo(a0.x) * wd[0] + bfhi(a0.x) * wd[1] + bflo(a0.y) * wd[2] +
               bfhi(a0.y) * wd[3] + bflo(a0.z) * wd[4] + bfhi(a0.z) * wd[5] +
               bflo(a0.w) * wd[6] + bfhi(a0.w) * wd[7] + bflo(a1.x) * wd[8] +
               bfhi(a1.x) * wd[9] + bflo(a1.y) * wd[10] + bfhi(a1.y) * wd[11] +
               bflo(a1.z) * wd[12] + bfhi(a1.z) * wd[13] + bflo(a1.w) * wd[14] +
               bfhi(a1.w) * wd[15];
    float p1 = bflo(c0.x) * wd[0] + bfhi(c0.x) * wd[1] + bflo(c0.y) * wd[2] +
               bfhi(c0.y) * wd[3] + bflo(c0.z) * wd[4] + bfhi(c0.z) * wd[5] +
               bflo(c0.w) * wd[6] + bfhi(c0.w) * wd[7] + bflo(c1.x) * wd[8] +
               bfhi(c1.x) * wd[9] + bflo(c1.y) * wd[10] + bfhi(c1.y) * wd[11] +
               bflo(c1.z) * wd[12] + bfhi(c1.z) * wd[13] + bflo(c1.w) * wd[14] +
               bfhi(c1.w) * wd[15];
#pragma unroll
    for (int off = 1; off <= 8; off <<= 1) {
      p0 += __shfl_xor(p0, off);
      p1 += __shfl_xor(p1, off);
    }
    if (l == 0) {
      if (id0 >= 0) out[id0] = p0 + b;
      if (id1 >= 0) out[id1] = p1 + b;
    }
  }
}

extern "C" void kernel_launch(void* const* d_in, const int* in_sizes, int n_in,
                              void* d_out, int out_size, void* d_ws, size_t ws_size,
                              hipStream_t stream) {
  const float* x  = (const float*)d_in[0];
  const int* ei   = (const int*)d_in[1];
  const float* W1 = (const float*)d_in[3];
  const float* as1 = (const float*)d_in[4];
  const float* ad1 = (const float*)d_in[5];
  const float* b1 = (const float*)d_in[6];
  const float* W2 = (const float*)d_in[7];
  const float* as2 = (const float*)d_in[8];
  const float* ad2 = (const float*)d_in[9];
  const float* b2 = (const float*)d_in[10];
  const float* We = (const float*)d_in[11];
  const float* be = (const float*)d_in[12];
  const float* Wn = (const float*)d_in[13];
  const float* bn = (const float*)d_in[14];
  float* out = (float*)d_out;

  char* wsp = (char*)d_ws;
  auto alloc = [&](size_t bytes) {
    char* p = wsp;
    wsp += (bytes + 255) & ~(size_t)255;
    return p;
  };
  unsigned short* hbA = (unsigned short*)alloc((size_t)NN * HC * 2); // gemm out bf16 (both layers)
  unsigned short* h1b = (unsigned short*)alloc((size_t)NN * HC * 2); // agg1 out bf16 (xh aliases)
  unsigned short* hbB = (unsigned short*)alloc((size_t)NN * HC * 2); // agg2 out bf16
  float* a_s = (float*)alloc((size_t)NN * 8 * 4);
  float* a_d = (float*)alloc((size_t)NN * 8 * 4);
  int* rowptr = (int*)alloc((size_t)(NN + 1) * 4);
  int* colv = (int*)alloc((size_t)(NE + NN + 8) * 4);
  int* eidv = (int*)alloc((size_t)(NE + NN + 8) * 4);
  int* counts = (int*)alloc((size_t)NN * 4);   // reused for W1t after CSR build
  int* tmp = (int*)alloc((size_t)NN * 4);      // reused for W2th after CSR build
  int* scanbuf = (int*)alloc((size_t)NN * 4);  // reused for W2tl after CSR build
  int* bsum = (int*)alloc(256 * 4);
  int* boff = (int*)alloc(256 * 4);

  // aliases (lifetimes disjoint):
  unsigned short* xh = h1b;  // x bf16 dead once gemm1 consumed it; agg1 then writes h1b
  unsigned short* W1th = (unsigned short*)counts;
  unsigned short* W1tl = (unsigned short*)counts + FIN * HC;
  unsigned short* W2th = (unsigned short*)tmp;
  unsigned short* W2tl = (unsigned short*)scanbuf;

  const int NB = (NN + 255) / 256;

  // CSR build (counts/tmp zeroed by memset; self-loop +1 folded into scan1)
  hipMemsetAsync(counts, 0, (size_t)NN * 4, stream);
  hipMemsetAsync(tmp, 0, (size_t)NN * 4, stream);
  hist_kernel<<<(NE + 255) / 256, 256, 0, stream>>>(ei, counts);
  scan1<<<NB, 256, 0, stream>>>(counts, scanbuf, bsum);
  scan2<<<1, 256, 0, stream>>>(bsum, boff, NB);
  scan3<<<NB, 256, 0, stream>>>(scanbuf, boff, rowptr);
  scatter_kernel<<<(NE + NN + 255) / 256, 256, 0, stream>>>(ei, rowptr, tmp, colv, eidv);

  // conversions (after CSR build so the scratch overlay is safe)
  convert_x<<<(NN * FIN / 4 + 255) / 256, 256, 0, stream>>>(x, xh, NN * FIN / 4);
  convert_w<<<(FIN * HC + 255) / 256, 256, 0, stream>>>(W1, W1th, W1tl, FIN);
  convert_w<<<(HC * HC + 255) / 256, 256, 0, stream>>>(W2, W2th, W2tl, HC);

  dim3 ggrid((NN + 127) / 128, 2);

  // layer 1 (coef fused into gemm epilogue via shuffle reduce)
  gemm_coef<<<ggrid, 256, 0, stream>>>(xh, W1th, W1tl, as1, ad1, hbA, a_s, a_d, NN, FIN);
  agg_kernel<<<NN / 8, 256, 0, stream>>>(hbA, a_s, a_d, rowptr, colv, b1, h1b,
                                         (const float*)nullptr, (const float*)nullptr,
                                         (float*)nullptr);

  // layer 2 (coef fused; node_pred fused into agg epilogue)
  gemm_coef<<<ggrid, 256, 0, stream>>>(h1b, W2th, W2tl, as2, ad2, hbA, a_s, a_d, NN, HC);
  agg_kernel<<<NN / 8, 256, 0, stream>>>(hbA, a_s, a_d, rowptr, colv, b2, hbB,
                                         Wn, bn, out + NE);

  // edge predictions
  edge_pred_kernel<<<NN / 4, 256, 0, stream>>>(hbB, rowptr, colv, eidv, We, be, out);
}

// Round 10
// 460.608 us; speedup vs baseline: 1.8955x; 1.0199x over previous
//
#include <hip/hip_runtime.h>
#include <hip/hip_bf16.h>

#define NN 50000
#define NE 800000
#define FIN 128
#define HC 256
#define NEG_SLOPE 0.2f

#define GEMM_BLOCKS 782   // ceil(NN/128)*2
#define NSB 3321          // ceil((NE+NN)/256) scatter blocks
#define NB_ZERO 196       // ceil(NN/256)
#define NB_X 6250         // NN*FIN/4/256
#define NB_W1 128         // FIN*HC/256
#define NB_W2 256         // HC*HC/256

typedef short bf16x8 __attribute__((ext_vector_type(8)));
typedef float f32x4 __attribute__((ext_vector_type(4)));

__device__ __forceinline__ unsigned short f2bf(float f) {
  unsigned u = __float_as_uint(f);
  u += 0x7fff + ((u >> 16) & 1);  // RTN-even
  return (unsigned short)(u >> 16);
}
__device__ __forceinline__ float bf2f(unsigned short s) {
  return __uint_as_float((unsigned)s << 16);
}
__device__ __forceinline__ float bflo(unsigned u) { return __uint_as_float(u << 16); }
__device__ __forceinline__ float bfhi(unsigned u) { return __uint_as_float(u & 0xffff0000u); }

// ---------------- fused prep: zero counts/tmp + convert x + transpose/split W1,W2 ----
__global__ __launch_bounds__(256) void prep_kernel(
    const float* __restrict__ X, unsigned short* __restrict__ Xh,
    const float* __restrict__ W1, unsigned short* __restrict__ W1th,
    unsigned short* __restrict__ W1tl, const float* __restrict__ W2,
    unsigned short* __restrict__ W2th, unsigned short* __restrict__ W2tl,
    int* __restrict__ counts, int* __restrict__ tmp) {
  int b = blockIdx.x, t = threadIdx.x;
  if (b < NB_ZERO) {
    int i = b * 256 + t;
    if (i < NN) { counts[i] = 0; tmp[i] = 0; }
  } else if (b < NB_ZERO + NB_X) {
    int i = (b - NB_ZERO) * 256 + t;  // exact: NN*FIN/4 = 1.6M
    float4 v = ((const float4*)X)[i];
    ushort4 h;
    h.x = f2bf(v.x); h.y = f2bf(v.y); h.z = f2bf(v.z); h.w = f2bf(v.w);
    ((ushort4*)Xh)[i] = h;
  } else if (b < NB_ZERO + NB_X + NB_W1) {
    int j = (b - NB_ZERO - NB_X) * 256 + t;  // j = n*K+k, output-contiguous, K=128
    int n = j >> 7, k = j & 127;
    float v = W1[k * HC + n];
    unsigned short h = f2bf(v);
    W1th[j] = h;
    W1tl[j] = f2bf(v - bf2f(h));
  } else {
    int j = (b - NB_ZERO - NB_X - NB_W1) * 256 + t;  // K=256
    int n = j >> 8, k = j & 255;
    float v = W2[k * HC + n];
    unsigned short h = f2bf(v);
    W2th[j] = h;
    W2tl[j] = f2bf(v - bf2f(h));
  }
}

// ---------------- MFMA GEMM + fused coef, LDS-transposed epilogue ----------------
// Cb(bf16) = A_bf16 @ (Bh+Bl)^T(stored [N][K]); 2-term split.
// A fragments read DIRECT from global (row-contiguous 16B = MFMA A layout) - no sA.
// Epilogue: C tile -> LDS (stride 136 shorts, 16B-aligned rows) -> 8 dwordx4 stores
// per thread + per-(row,head) coef dots computed locally (no shuffles/atomics;
// round-8's LDS atomics were 243us, round-9's 256 shuffle-ops were the residue).
// Optionally fuses the CSR scatter into trailing blocks (independent work).
__global__ __launch_bounds__(256) void gemm_coef(
    const unsigned short* __restrict__ A, const unsigned short* __restrict__ Bth,
    const unsigned short* __restrict__ Btl, const float* __restrict__ att_s,
    const float* __restrict__ att_d, unsigned short* __restrict__ Cb,
    float* __restrict__ a_s, float* __restrict__ a_d, int M, int K,
    const int* __restrict__ ei, const int* __restrict__ rowptr,
    int* __restrict__ tmpc, int2* __restrict__ ce) {
  __shared__ unsigned short smem[128 * 136];  // 34816 B: B-staging (10240) then C tile

  int bid = blockIdx.x, t = threadIdx.x;
  if (bid >= GEMM_BLOCKS) {
    // fused scatter path (layer-1 launch only)
    int e = (bid - GEMM_BLOCKS) * 256 + t;
    if (e < NE + NN) {
      int s, d, id;
      if (e < NE) { s = ei[e]; d = ei[NE + e]; id = e; }
      else { s = d = e - NE; id = -1; }
      int pos = rowptr[d] + atomicAdd(&tmpc[d], 1);
      ce[pos] = make_int2(s, id);
    }
    return;
  }

  int w = t >> 6, lane = t & 63;
  int quad = lane >> 4, lrow = lane & 15;
  int m0 = (bid >> 1) * 128, n0 = (bid & 1) * 128;
  int wm = (w >> 1) * 64, wn = (w & 1) * 64;

  // A row base pointers (clamped tail rows duplicate row M-1; results discarded)
  const unsigned short* arow[4];
#pragma unroll
  for (int mi = 0; mi < 4; ++mi) {
    int gm = m0 + wm + mi * 16 + lrow;
    if (gm >= M) gm = M - 1;
    arow[mi] = A + (size_t)gm * K + quad * 8;
  }

  f32x4 acc[4][4] = {};

  for (int k0 = 0; k0 < K; k0 += 32) {
    // stage B tiles only (sBh = smem[0..5120), sBl = smem[5120..10240))
#pragma unroll
    for (int i = 0; i < 2; ++i) {
      int idx = t + i * 256;
      int row = idx >> 2, q = idx & 3;
      size_t gb = (size_t)(n0 + row) * K + k0 + q * 8;
      *(uint4*)(smem + row * 40 + q * 8) = *(const uint4*)(Bth + gb);
      *(uint4*)(smem + 5120 + row * 40 + q * 8) = *(const uint4*)(Btl + gb);
    }
    __syncthreads();

    bf16x8 fa[4];
#pragma unroll
    for (int mi = 0; mi < 4; ++mi) fa[mi] = *(const bf16x8*)(arow[mi] + k0);
#pragma unroll
    for (int ni = 0; ni < 4; ++ni) {
      bf16x8 fbh = *(const bf16x8*)(smem + (wn + ni * 16 + lrow) * 40 + quad * 8);
      bf16x8 fbl = *(const bf16x8*)(smem + 5120 + (wn + ni * 16 + lrow) * 40 + quad * 8);
#pragma unroll
      for (int mi = 0; mi < 4; ++mi) {
        acc[mi][ni] = __builtin_amdgcn_mfma_f32_16x16x32_bf16(fa[mi], fbh, acc[mi][ni], 0, 0, 0);
        acc[mi][ni] = __builtin_amdgcn_mfma_f32_16x16x32_bf16(fa[mi], fbl, acc[mi][ni], 0, 0, 0);
      }
    }
    __syncthreads();  // also guards the smem reuse below on the last iter
  }

  // C/D layout: col = lane&15, row = quad*4 + reg  [m89-verified]
  // stage C tile (bf16) into LDS, stride 136 shorts (272 B: 16B-aligned, quads land
  // on disjoint-ish bank groups)
#pragma unroll
  for (int mi = 0; mi < 4; ++mi) {
#pragma unroll
    for (int r = 0; r < 4; ++r) {
      int row = wm + mi * 16 + quad * 4 + r;
#pragma unroll
      for (int ni = 0; ni < 4; ++ni) {
        int col = wn + ni * 16 + lrow;
        smem[row * 136 + col] = f2bf(acc[mi][ni][r]);
      }
    }
  }
  __syncthreads();

  // coalesced writeback + local coef dots: thread = (row, half of 128 cols)
  {
    int row = t >> 1, half = t & 1;
    int gm = m0 + row;
    if (gm < M) {
      float ps0 = 0.f, ps1 = 0.f, pd0 = 0.f, pd1 = 0.f;
#pragma unroll
      for (int j = 0; j < 8; ++j) {
        uint4 v = *(const uint4*)(smem + row * 136 + half * 64 + j * 8);
        int gc = n0 + half * 64 + j * 8;
        *(uint4*)(Cb + (size_t)gm * HC + gc) = v;  // 8 packed bf16
        float4 s0 = *(const float4*)(att_s + gc);
        float4 s1 = *(const float4*)(att_s + gc + 4);
        float4 d0 = *(const float4*)(att_d + gc);
        float4 d1 = *(const float4*)(att_d + gc + 4);
        float f0 = bflo(v.x), f1 = bfhi(v.x), f2 = bflo(v.y), f3 = bfhi(v.y);
        float f4 = bflo(v.z), f5 = bfhi(v.z), f6 = bflo(v.w), f7 = bfhi(v.w);
        float ss = f0 * s0.x + f1 * s0.y + f2 * s0.z + f3 * s0.w +
                   f4 * s1.x + f5 * s1.y + f6 * s1.z + f7 * s1.w;
        float dd = f0 * d0.x + f1 * d0.y + f2 * d0.z + f3 * d0.w +
                   f4 * d1.x + f5 * d1.y + f6 * d1.z + f7 * d1.w;
        if (j < 4) { ps0 += ss; pd0 += dd; }
        else       { ps1 += ss; pd1 += dd; }
      }
      int hb2 = (n0 >> 5) + half * 2;  // this thread's 2 heads
      a_s[gm * 8 + hb2] = ps0;
      a_s[gm * 8 + hb2 + 1] = ps1;
      a_d[gm * 8 + hb2] = pd0;
      a_d[gm * 8 + hb2 + 1] = pd1;
    }
  }
}

// ---------------- CSR build ----------------
__global__ void hist_kernel(const int* __restrict__ ei, int* __restrict__ counts) {
  int e = blockIdx.x * 256 + threadIdx.x;
  if (e < NE) atomicAdd(&counts[ei[NE + e]], 1);
}

__global__ void scan1(const int* __restrict__ counts, int* __restrict__ scanbuf,
                      int* __restrict__ bsum) {
  __shared__ int sd[256];
  int t = threadIdx.x;
  int i = blockIdx.x * 256 + t;
  int v = (i < NN) ? counts[i] + 1 : 0;  // +1 = self-loop
  sd[t] = v;
  __syncthreads();
#pragma unroll
  for (int off = 1; off < 256; off <<= 1) {
    int x = (t >= off) ? sd[t - off] : 0;
    __syncthreads();
    sd[t] += x;
    __syncthreads();
  }
  if (i < NN) scanbuf[i] = sd[t];
  if (t == 255) bsum[blockIdx.x] = sd[255];
}

__global__ void scan2(const int* __restrict__ bsum, int* __restrict__ boff, int nb) {
  __shared__ int sd[256];
  int t = threadIdx.x;
  int v = (t < nb) ? bsum[t] : 0;
  sd[t] = v;
  __syncthreads();
#pragma unroll
  for (int off = 1; off < 256; off <<= 1) {
    int x = (t >= off) ? sd[t - off] : 0;
    __syncthreads();
    sd[t] += x;
    __syncthreads();
  }
  if (t < nb) boff[t] = sd[t] - v;  // exclusive
}

__global__ void scan3(const int* __restrict__ scanbuf, const int* __restrict__ boff,
                      int* __restrict__ rowptr) {
  int i = blockIdx.x * 256 + threadIdx.x;
  if (i < NN) rowptr[i + 1] = scanbuf[i] + boff[blockIdx.x];
  if (i == 0) rowptr[0] = 0;
}

// ---------------- aggregation: 32 lanes/dst, masked 4-edge unroll, no-max softmax ----
__global__ __launch_bounds__(256) void agg_kernel(
    const unsigned short* __restrict__ htb, const float* __restrict__ a_s,
    const float* __restrict__ a_d, const int* __restrict__ rowptr,
    const int2* __restrict__ ce, const float* __restrict__ bias,
    unsigned short* __restrict__ outb,
    const float* __restrict__ Wn, const float* __restrict__ bn,
    float* __restrict__ outn) {
  int d = blockIdx.x * 8 + (threadIdx.x >> 5);
  if (d >= NN) return;
  int l = threadIdx.x & 31;
  int hh = l >> 2;
  float adh = a_d[d * 8 + hh];
  int r0 = rowptr[d], r1 = rowptr[d + 1];
  float denom = 0.f;
  float4 acc0 = {0.f, 0.f, 0.f, 0.f};
  float4 acc1 = {0.f, 0.f, 0.f, 0.f};
  for (int r = r0; r < r1; r += 4) {
    int s[4];
    float as_[4];
    uint4 q[4];
    bool ok[4];
#pragma unroll
    for (int j = 0; j < 4; ++j) {
      int rj = r + j;
      ok[j] = rj < r1;
      rj = ok[j] ? rj : r1 - 1;  // clamp: duplicate load, weight zeroed
      s[j] = ce[rj].x;
    }
#pragma unroll
    for (int j = 0; j < 4; ++j) {
      as_[j] = a_s[s[j] * 8 + hh];
      q[j] = ((const uint4*)(htb + (size_t)s[j] * HC))[l];
    }
#pragma unroll
    for (int j = 0; j < 4; ++j) {
      float e = as_[j] + adh;
      e = e > 0.f ? e : NEG_SLOPE * e;
      float w = ok[j] ? __expf(e) : 0.f;
      denom += w;
      acc0.x += w * bflo(q[j].x);
      acc0.y += w * bfhi(q[j].x);
      acc0.z += w * bflo(q[j].y);
      acc0.w += w * bfhi(q[j].y);
      acc1.x += w * bflo(q[j].z);
      acc1.y += w * bfhi(q[j].z);
      acc1.z += w * bflo(q[j].w);
      acc1.w += w * bfhi(q[j].w);
    }
  }
  float dv = 1.f / denom;  // denom >= 1 (self-loop)
  float4 b0 = *(const float4*)(bias + l * 8);
  float4 b1 = *(const float4*)(bias + l * 8 + 4);
  float4 o0, o1;
  o0.x = fmaxf(fmaf(acc0.x, dv, b0.x), 0.f);
  o0.y = fmaxf(fmaf(acc0.y, dv, b0.y), 0.f);
  o0.z = fmaxf(fmaf(acc0.z, dv, b0.z), 0.f);
  o0.w = fmaxf(fmaf(acc0.w, dv, b0.w), 0.f);
  o1.x = fmaxf(fmaf(acc1.x, dv, b1.x), 0.f);
  o1.y = fmaxf(fmaf(acc1.y, dv, b1.y), 0.f);
  o1.z = fmaxf(fmaf(acc1.z, dv, b1.z), 0.f);
  o1.w = fmaxf(fmaf(acc1.w, dv, b1.w), 0.f);
  uint4 pb;
  pb.x = (unsigned)f2bf(o0.x) | ((unsigned)f2bf(o0.y) << 16);
  pb.y = (unsigned)f2bf(o0.z) | ((unsigned)f2bf(o0.w) << 16);
  pb.z = (unsigned)f2bf(o1.x) | ((unsigned)f2bf(o1.y) << 16);
  pb.w = (unsigned)f2bf(o1.z) | ((unsigned)f2bf(o1.w) << 16);
  ((uint4*)(outb + (size_t)d * HC))[l] = pb;
  if (outn) {
    const float4* wnp = (const float4*)(Wn + l * 8);
    float4 w0 = wnp[0], w1 = wnp[1];
    float p = o0.x * w0.x + o0.y * w0.y + o0.z * w0.z + o0.w * w0.w +
              o1.x * w1.x + o1.y * w1.y + o1.z * w1.z + o1.w * w1.w;
#pragma unroll
    for (int off = 1; off <= 16; off <<= 1) p += __shfl_xor(p, off);
    if (l == 0) outn[d] = p + bn[0];
  }
}

// ---------------- edge predictions: 16-lane group per edge, 2-edge unroll ----------------
__global__ __launch_bounds__(256) void edge_pred_kernel(
    const unsigned short* __restrict__ h2b, const int* __restrict__ rowptr,
    const int2* __restrict__ ce, const float* __restrict__ We,
    const float* __restrict__ be, float* __restrict__ out) {
  int d = blockIdx.x * 4 + (threadIdx.x >> 6);
  if (d >= NN) return;
  int lane = threadIdx.x & 63;
  int g = lane >> 4, l = lane & 15;
  float b = be[0];

  const uint4* rowd = (const uint4*)(h2b + (size_t)d * HC + l * 16);
  uint4 qd0 = rowd[0], qd1 = rowd[1];
  float wd[16];
  {
    const float4* wep = (const float4*)(We + l * 16);
    float4 w0 = wep[0], w1 = wep[1], w2 = wep[2], w3 = wep[3];
    wd[0] = bflo(qd0.x) * w0.x;  wd[1] = bfhi(qd0.x) * w0.y;
    wd[2] = bflo(qd0.y) * w0.z;  wd[3] = bfhi(qd0.y) * w0.w;
    wd[4] = bflo(qd0.z) * w1.x;  wd[5] = bfhi(qd0.z) * w1.y;
    wd[6] = bflo(qd0.w) * w1.z;  wd[7] = bfhi(qd0.w) * w1.w;
    wd[8] = bflo(qd1.x) * w2.x;  wd[9] = bfhi(qd1.x) * w2.y;
    wd[10] = bflo(qd1.y) * w2.z; wd[11] = bfhi(qd1.y) * w2.w;
    wd[12] = bflo(qd1.z) * w3.x; wd[13] = bfhi(qd1.z) * w3.y;
    wd[14] = bflo(qd1.w) * w3.z; wd[15] = bfhi(qd1.w) * w3.w;
  }

  int r0 = rowptr[d], r1 = rowptr[d + 1];
  for (int r = r0; r < r1; r += 8) {
    int rr0 = r + g, rr1 = r + 4 + g;
    int s0 = 0, id0 = -1, s1 = 0, id1 = -1;
    if (rr0 < r1) { int2 p = ce[rr0]; s0 = p.x; id0 = p.y; }
    if (rr1 < r1) { int2 p = ce[rr1]; s1 = p.x; id1 = p.y; }
    const uint4* ra = (const uint4*)(h2b + (size_t)s0 * HC + l * 16);
    const uint4* rb = (const uint4*)(h2b + (size_t)s1 * HC + l * 16);
    uint4 a0 = ra[0], a1 = ra[1];
    uint4 c0 = rb[0], c1 = rb[1];
    float p0 = bflo(a0.x) * wd[0] + bfhi(a0.x) * wd[1] + bflo(a0.y) * wd[2] +
               bfhi(a0.y) * wd[3] + bflo(a0.z) * wd[4] + bfhi(a0.z) * wd[5] +
               bflo(a0.w) * wd[6] + bfhi(a0.w) * wd[7] + bflo(a1.x) * wd[8] +
               bfhi(a1.x) * wd[9] + bflo(a1.y) * wd[10] + bfhi(a1.y) * wd[11] +
               bflo(a1.z) * wd[12] + bfhi(a1.z) * wd[13] + bflo(a1.w) * wd[14] +
               bfhi(a1.w) * wd[15];
    float p1 = bflo(c0.x) * wd[0] + bfhi(c0.x) * wd[1] + bflo(c0.y) * wd[2] +
               bfhi(c0.y) * wd[3] + bflo(c0.z) * wd[4] + bfhi(c0.z) * wd[5] +
               bflo(c0.w) * wd[6] + bfhi(c0.w) * wd[7] + bflo(c1.x) * wd[8] +
               bfhi(c1.x) * wd[9] + bflo(c1.y) * wd[10] + bfhi(c1.y) * wd[11] +
               bflo(c1.z) * wd[12] + bfhi(c1.z) * wd[13] + bflo(c1.w) * wd[14] +
               bfhi(c1.w) * wd[15];
#pragma unroll
    for (int off = 1; off <= 8; off <<= 1) {
      p0 += __shfl_xor(p0, off);
      p1 += __shfl_xor(p1, off);
    }
    if (l == 0) {
      if (id0 >= 0) out[id0] = p0 + b;
      if (id1 >= 0) out[id1] = p1 + b;
    }
  }
}

extern "C" void kernel_launch(void* const* d_in, const int* in_sizes, int n_in,
                              void* d_out, int out_size, void* d_ws, size_t ws_size,
                              hipStream_t stream) {
  const float* x  = (const float*)d_in[0];
  const int* ei   = (const int*)d_in[1];
  const float* W1 = (const float*)d_in[3];
  const float* as1 = (const float*)d_in[4];
  const float* ad1 = (const float*)d_in[5];
  const float* b1 = (const float*)d_in[6];
  const float* W2 = (const float*)d_in[7];
  const float* as2 = (const float*)d_in[8];
  const float* ad2 = (const float*)d_in[9];
  const float* b2 = (const float*)d_in[10];
  const float* We = (const float*)d_in[11];
  const float* be = (const float*)d_in[12];
  const float* Wn = (const float*)d_in[13];
  const float* bn = (const float*)d_in[14];
  float* out = (float*)d_out;

  char* wsp = (char*)d_ws;
  auto alloc = [&](size_t bytes) {
    char* p = wsp;
    wsp += (bytes + 255) & ~(size_t)255;
    return p;
  };
  unsigned short* hbA = (unsigned short*)alloc((size_t)NN * HC * 2); // gemm out (both layers)
  unsigned short* h1b = (unsigned short*)alloc((size_t)NN * HC * 2); // agg1 out (xh aliases)
  unsigned short* hbB = (unsigned short*)alloc((size_t)NN * HC * 2); // agg2 out
  float* a_s = (float*)alloc((size_t)NN * 8 * 4);
  float* a_d = (float*)alloc((size_t)NN * 8 * 4);
  int* rowptr = (int*)alloc((size_t)(NN + 1) * 4);
  int2* ce = (int2*)alloc((size_t)(NE + NN + 8) * 8);  // (src, edge-id) pairs
  int* counts = (int*)alloc((size_t)NN * 4);
  int* tmp = (int*)alloc((size_t)NN * 4);
  int* scanbuf = (int*)alloc((size_t)NN * 4);
  int* bsum = (int*)alloc(256 * 4);
  int* boff = (int*)alloc(256 * 4);
  unsigned short* W1th = (unsigned short*)alloc((size_t)FIN * HC * 2);
  unsigned short* W1tl = (unsigned short*)alloc((size_t)FIN * HC * 2);
  unsigned short* W2th = (unsigned short*)alloc((size_t)HC * HC * 2);
  unsigned short* W2tl = (unsigned short*)alloc((size_t)HC * HC * 2);

  unsigned short* xh = h1b;  // x bf16 consumed by gemm1 before agg1 writes h1b

  const int NB = (NN + 255) / 256;

  // prep: zero counters + all dtype conversions (one launch)
  prep_kernel<<<NB_ZERO + NB_X + NB_W1 + NB_W2, 256, 0, stream>>>(
      x, xh, W1, W1th, W1tl, W2, W2th, W2tl, counts, tmp);
  // CSR build
  hist_kernel<<<(NE + 255) / 256, 256, 0, stream>>>(ei, counts);
  scan1<<<NB, 256, 0, stream>>>(counts, scanbuf, bsum);
  scan2<<<1, 256, 0, stream>>>(bsum, boff, NB);
  scan3<<<NB, 256, 0, stream>>>(scanbuf, boff, rowptr);

  // layer 1 gemm+coef, with CSR scatter fused into trailing blocks
  gemm_coef<<<GEMM_BLOCKS + NSB, 256, 0, stream>>>(
      xh, W1th, W1tl, as1, ad1, hbA, a_s, a_d, NN, FIN, ei, rowptr, tmp, ce);
  agg_kernel<<<NN / 8, 256, 0, stream>>>(hbA, a_s, a_d, rowptr, ce, b1, h1b,
                                         (const float*)nullptr, (const float*)nullptr,
                                         (float*)nullptr);

  // layer 2 (node_pred fused into agg epilogue)
  gemm_coef<<<GEMM_BLOCKS, 256, 0, stream>>>(
      h1b, W2th, W2tl, as2, ad2, hbA, a_s, a_d, NN, HC,
      (const int*)nullptr, rowptr, tmp, ce);
  agg_kernel<<<NN / 8, 256, 0, stream>>>(hbA, a_s, a_d, rowptr, ce, b2, hbB,
                                         Wn, bn, out + NE);

  // edge predictions
  edge_pred_kernel<<<NN / 4, 256, 0, stream>>>(hbB, rowptr, ce, We, be, out);
}

// Round 11
// 446.254 us; speedup vs baseline: 1.9565x; 1.0322x over previous
//
#include <hip/hip_runtime.h>
#include <hip/hip_bf16.h>

#define NN 50000
#define NE 800000
#define FIN 128
#define HC 256
#define NEG_SLOPE 0.2f

#define GEMM_BLOCKS 782   // ceil(NN/128)*2
#define NSB 3321          // ceil((NE+NN)/256) scatter blocks
#define NB_ZERO 196       // ceil(NN/256)
#define NB_X 6250         // NN*FIN/4/256
#define NB_W1 128         // FIN*HC/256
#define NB_W2 256         // HC*HC/256

typedef short bf16x8 __attribute__((ext_vector_type(8)));
typedef float f32x4 __attribute__((ext_vector_type(4)));

__device__ __forceinline__ unsigned short f2bf(float f) {
  unsigned u = __float_as_uint(f);
  u += 0x7fff + ((u >> 16) & 1);  // RTN-even
  return (unsigned short)(u >> 16);
}
__device__ __forceinline__ float bf2f(unsigned short s) {
  return __uint_as_float((unsigned)s << 16);
}
__device__ __forceinline__ float bflo(unsigned u) { return __uint_as_float(u << 16); }
__device__ __forceinline__ float bfhi(unsigned u) { return __uint_as_float(u & 0xffff0000u); }

// ---------------- fused prep: zero counts/tmp + convert x + transpose/split W1,W2 ----
__global__ __launch_bounds__(256) void prep_kernel(
    const float* __restrict__ X, unsigned short* __restrict__ Xh,
    const float* __restrict__ W1, unsigned short* __restrict__ W1th,
    unsigned short* __restrict__ W1tl, const float* __restrict__ W2,
    unsigned short* __restrict__ W2th, unsigned short* __restrict__ W2tl,
    int* __restrict__ counts, int* __restrict__ tmp) {
  int b = blockIdx.x, t = threadIdx.x;
  if (b < NB_ZERO) {
    int i = b * 256 + t;
    if (i < NN) { counts[i] = 0; tmp[i] = 0; }
  } else if (b < NB_ZERO + NB_X) {
    int i = (b - NB_ZERO) * 256 + t;  // exact: NN*FIN/4 = 1.6M
    float4 v = ((const float4*)X)[i];
    ushort4 h;
    h.x = f2bf(v.x); h.y = f2bf(v.y); h.z = f2bf(v.z); h.w = f2bf(v.w);
    ((ushort4*)Xh)[i] = h;
  } else if (b < NB_ZERO + NB_X + NB_W1) {
    int j = (b - NB_ZERO - NB_X) * 256 + t;  // j = n*K+k, output-contiguous, K=128
    int n = j >> 7, k = j & 127;
    float v = W1[k * HC + n];
    unsigned short h = f2bf(v);
    W1th[j] = h;
    W1tl[j] = f2bf(v - bf2f(h));
  } else {
    int j = (b - NB_ZERO - NB_X - NB_W1) * 256 + t;  // K=256
    int n = j >> 8, k = j & 255;
    float v = W2[k * HC + n];
    unsigned short h = f2bf(v);
    W2th[j] = h;
    W2tl[j] = f2bf(v - bf2f(h));
  }
}

// ---------------- MFMA GEMM + fused coef (round-9 proven shape) ----------------
// Cb(bf16) = A_bf16 @ (Bh+Bl)^T(stored [N][K]); 2-term split; sA/sB LDS-staged
// (coalesced uint4), coef via 16-lane shuffle reduce, C stored as quad-contiguous
// 2B scalars (full 32B sectors — round-10's 16B/512B-stride stores amplified
// WRITE_SIZE 29->85MB and regressed 60->83us; do not repeat).
// Trailing blocks (layer-1 launch) run the CSR scatter — independent work.
__global__ __launch_bounds__(256) void gemm_coef(
    const unsigned short* __restrict__ A, const unsigned short* __restrict__ Bth,
    const unsigned short* __restrict__ Btl, const float* __restrict__ att_s,
    const float* __restrict__ att_d, unsigned short* __restrict__ Cb,
    float* __restrict__ a_s, float* __restrict__ a_d, int M, int K,
    const int* __restrict__ ei, const int* __restrict__ rowptr,
    int* __restrict__ tmpc, int2* __restrict__ ce) {
  __shared__ unsigned short sA[128 * 40];   // stride 40 shorts: <=2-way banks (free)
  __shared__ unsigned short sBh[128 * 40];
  __shared__ unsigned short sBl[128 * 40];

  int bid = blockIdx.x, t = threadIdx.x;
  if (bid >= GEMM_BLOCKS) {
    // fused scatter path (layer-1 launch only)
    int e = (bid - GEMM_BLOCKS) * 256 + t;
    if (e < NE + NN) {
      int s, d, id;
      if (e < NE) { s = ei[e]; d = ei[NE + e]; id = e; }
      else { s = d = e - NE; id = -1; }
      int pos = rowptr[d] + atomicAdd(&tmpc[d], 1);
      ce[pos] = make_int2(s, id);
    }
    return;
  }

  int w = t >> 6, lane = t & 63;
  int quad = lane >> 4, lrow = lane & 15;
  int m0 = (bid >> 1) * 128, n0 = (bid & 1) * 128;
  int wm = (w >> 1) * 64, wn = (w & 1) * 64;

  f32x4 acc[4][4] = {};

  for (int k0 = 0; k0 < K; k0 += 32) {
#pragma unroll
    for (int i = 0; i < 2; ++i) {
      int idx = t + i * 256;           // 0..511
      int row = idx >> 2, q = idx & 3;
      int gm = m0 + row;
      if (gm >= M) gm = M - 1;
      size_t ga = (size_t)gm * K + k0 + q * 8;
      size_t gb = (size_t)(n0 + row) * K + k0 + q * 8;
      *(uint4*)(sA + row * 40 + q * 8) = *(const uint4*)(A + ga);
      *(uint4*)(sBh + row * 40 + q * 8) = *(const uint4*)(Bth + gb);
      *(uint4*)(sBl + row * 40 + q * 8) = *(const uint4*)(Btl + gb);
    }
    __syncthreads();

    bf16x8 fa[4];
#pragma unroll
    for (int mi = 0; mi < 4; ++mi)
      fa[mi] = *(const bf16x8*)(sA + (wm + mi * 16 + lrow) * 40 + quad * 8);
#pragma unroll
    for (int ni = 0; ni < 4; ++ni) {
      bf16x8 fbh = *(const bf16x8*)(sBh + (wn + ni * 16 + lrow) * 40 + quad * 8);
      bf16x8 fbl = *(const bf16x8*)(sBl + (wn + ni * 16 + lrow) * 40 + quad * 8);
#pragma unroll
      for (int mi = 0; mi < 4; ++mi) {
        acc[mi][ni] = __builtin_amdgcn_mfma_f32_16x16x32_bf16(fa[mi], fbh, acc[mi][ni], 0, 0, 0);
        acc[mi][ni] = __builtin_amdgcn_mfma_f32_16x16x32_bf16(fa[mi], fbl, acc[mi][ni], 0, 0, 0);
      }
    }
    __syncthreads();
  }

  // att values for this lane's 4 columns (hoisted)
  float vs[4], vd[4];
#pragma unroll
  for (int ni = 0; ni < 4; ++ni) {
    int gn = n0 + wn + ni * 16 + lrow;
    vs[ni] = att_s[gn];
    vd[ni] = att_d[gn];
  }
  int hb = (n0 + wn) >> 5;  // first head owned by this wave

  // C/D layout: col = lane&15, row = quad*4 + reg  [m89-verified]
#pragma unroll
  for (int mi = 0; mi < 4; ++mi) {
#pragma unroll
    for (int r = 0; r < 4; ++r) {
      int gm = m0 + wm + mi * 16 + quad * 4 + r;
      bool rowok = gm < M;
      if (rowok) {
#pragma unroll
        for (int ni = 0; ni < 4; ++ni) {
          int gn = n0 + wn + ni * 16 + lrow;
          Cb[(size_t)gm * HC + gn] = f2bf(acc[mi][ni][r]);
        }
      }
      // per-head partial dots: ni 0,1 -> head hb ; ni 2,3 -> head hb+1
      float pse = acc[mi][0][r] * vs[0] + acc[mi][1][r] * vs[1];
      float pso = acc[mi][2][r] * vs[2] + acc[mi][3][r] * vs[3];
      float pde = acc[mi][0][r] * vd[0] + acc[mi][1][r] * vd[1];
      float pdo = acc[mi][2][r] * vd[2] + acc[mi][3][r] * vd[3];
#pragma unroll
      for (int off = 1; off <= 8; off <<= 1) {
        pse += __shfl_xor(pse, off);
        pso += __shfl_xor(pso, off);
        pde += __shfl_xor(pde, off);
        pdo += __shfl_xor(pdo, off);
      }
      if (lrow == 0 && rowok) {
        a_s[gm * 8 + hb] = pse;
        a_s[gm * 8 + hb + 1] = pso;
        a_d[gm * 8 + hb] = pde;
        a_d[gm * 8 + hb + 1] = pdo;
      }
    }
  }
}

// ---------------- CSR build ----------------
__global__ void hist_kernel(const int* __restrict__ ei, int* __restrict__ counts) {
  int e = blockIdx.x * 256 + threadIdx.x;
  if (e < NE) atomicAdd(&counts[ei[NE + e]], 1);
}

__global__ void scan1(const int* __restrict__ counts, int* __restrict__ scanbuf,
                      int* __restrict__ bsum) {
  __shared__ int sd[256];
  int t = threadIdx.x;
  int i = blockIdx.x * 256 + t;
  int v = (i < NN) ? counts[i] + 1 : 0;  // +1 = self-loop
  sd[t] = v;
  __syncthreads();
#pragma unroll
  for (int off = 1; off < 256; off <<= 1) {
    int x = (t >= off) ? sd[t - off] : 0;
    __syncthreads();
    sd[t] += x;
    __syncthreads();
  }
  if (i < NN) scanbuf[i] = sd[t];
  if (t == 255) bsum[blockIdx.x] = sd[255];
}

__global__ void scan2(const int* __restrict__ bsum, int* __restrict__ boff, int nb) {
  __shared__ int sd[256];
  int t = threadIdx.x;
  int v = (t < nb) ? bsum[t] : 0;
  sd[t] = v;
  __syncthreads();
#pragma unroll
  for (int off = 1; off < 256; off <<= 1) {
    int x = (t >= off) ? sd[t - off] : 0;
    __syncthreads();
    sd[t] += x;
    __syncthreads();
  }
  if (t < nb) boff[t] = sd[t] - v;  // exclusive
}

__global__ void scan3(const int* __restrict__ scanbuf, const int* __restrict__ boff,
                      int* __restrict__ rowptr) {
  int i = blockIdx.x * 256 + threadIdx.x;
  if (i < NN) rowptr[i + 1] = scanbuf[i] + boff[blockIdx.x];
  if (i == 0) rowptr[0] = 0;
}

// ---------------- aggregation: 32 lanes/dst, masked 4-edge unroll, no-max softmax ----
__global__ __launch_bounds__(256) void agg_kernel(
    const unsigned short* __restrict__ htb, const float* __restrict__ a_s,
    const float* __restrict__ a_d, const int* __restrict__ rowptr,
    const int2* __restrict__ ce, const float* __restrict__ bias,
    unsigned short* __restrict__ outb,
    const float* __restrict__ Wn, const float* __restrict__ bn,
    float* __restrict__ outn) {
  int d = blockIdx.x * 8 + (threadIdx.x >> 5);
  if (d >= NN) return;
  int l = threadIdx.x & 31;
  int hh = l >> 2;
  float adh = a_d[d * 8 + hh];
  int r0 = rowptr[d], r1 = rowptr[d + 1];
  float denom = 0.f;
  float4 acc0 = {0.f, 0.f, 0.f, 0.f};
  float4 acc1 = {0.f, 0.f, 0.f, 0.f};
  for (int r = r0; r < r1; r += 4) {
    int s[4];
    float as_[4];
    uint4 q[4];
    bool ok[4];
#pragma unroll
    for (int j = 0; j < 4; ++j) {
      int rj = r + j;
      ok[j] = rj < r1;
      rj = ok[j] ? rj : r1 - 1;  // clamp: duplicate load, weight zeroed
      s[j] = ce[rj].x;
    }
#pragma unroll
    for (int j = 0; j < 4; ++j) {
      as_[j] = a_s[s[j] * 8 + hh];
      q[j] = ((const uint4*)(htb + (size_t)s[j] * HC))[l];
    }
#pragma unroll
    for (int j = 0; j < 4; ++j) {
      float e = as_[j] + adh;
      e = e > 0.f ? e : NEG_SLOPE * e;
      float w = ok[j] ? __expf(e) : 0.f;
      denom += w;
      acc0.x += w * bflo(q[j].x);
      acc0.y += w * bfhi(q[j].x);
      acc0.z += w * bflo(q[j].y);
      acc0.w += w * bfhi(q[j].y);
      acc1.x += w * bflo(q[j].z);
      acc1.y += w * bfhi(q[j].z);
      acc1.z += w * bflo(q[j].w);
      acc1.w += w * bfhi(q[j].w);
    }
  }
  float dv = 1.f / denom;  // denom >= 1 (self-loop)
  float4 b0 = *(const float4*)(bias + l * 8);
  float4 b1 = *(const float4*)(bias + l * 8 + 4);
  float4 o0, o1;
  o0.x = fmaxf(fmaf(acc0.x, dv, b0.x), 0.f);
  o0.y = fmaxf(fmaf(acc0.y, dv, b0.y), 0.f);
  o0.z = fmaxf(fmaf(acc0.z, dv, b0.z), 0.f);
  o0.w = fmaxf(fmaf(acc0.w, dv, b0.w), 0.f);
  o1.x = fmaxf(fmaf(acc1.x, dv, b1.x), 0.f);
  o1.y = fmaxf(fmaf(acc1.y, dv, b1.y), 0.f);
  o1.z = fmaxf(fmaf(acc1.z, dv, b1.z), 0.f);
  o1.w = fmaxf(fmaf(acc1.w, dv, b1.w), 0.f);
  uint4 pb;
  pb.x = (unsigned)f2bf(o0.x) | ((unsigned)f2bf(o0.y) << 16);
  pb.y = (unsigned)f2bf(o0.z) | ((unsigned)f2bf(o0.w) << 16);
  pb.z = (unsigned)f2bf(o1.x) | ((unsigned)f2bf(o1.y) << 16);
  pb.w = (unsigned)f2bf(o1.z) | ((unsigned)f2bf(o1.w) << 16);
  ((uint4*)(outb + (size_t)d * HC))[l] = pb;
  if (outn) {
    const float4* wnp = (const float4*)(Wn + l * 8);
    float4 w0 = wnp[0], w1 = wnp[1];
    float p = o0.x * w0.x + o0.y * w0.y + o0.z * w0.z + o0.w * w0.w +
              o1.x * w1.x + o1.y * w1.y + o1.z * w1.z + o1.w * w1.w;
#pragma unroll
    for (int off = 1; off <= 16; off <<= 1) p += __shfl_xor(p, off);
    if (l == 0) outn[d] = p + bn[0];
  }
}

// ---------------- edge predictions: 16-lane group per edge, 2-edge unroll ----------------
__global__ __launch_bounds__(256) void edge_pred_kernel(
    const unsigned short* __restrict__ h2b, const int* __restrict__ rowptr,
    const int2* __restrict__ ce, const float* __restrict__ We,
    const float* __restrict__ be, float* __restrict__ out) {
  int d = blockIdx.x * 4 + (threadIdx.x >> 6);
  if (d >= NN) return;
  int lane = threadIdx.x & 63;
  int g = lane >> 4, l = lane & 15;
  float b = be[0];

  const uint4* rowd = (const uint4*)(h2b + (size_t)d * HC + l * 16);
  uint4 qd0 = rowd[0], qd1 = rowd[1];
  float wd[16];
  {
    const float4* wep = (const float4*)(We + l * 16);
    float4 w0 = wep[0], w1 = wep[1], w2 = wep[2], w3 = wep[3];
    wd[0] = bflo(qd0.x) * w0.x;  wd[1] = bfhi(qd0.x) * w0.y;
    wd[2] = bflo(qd0.y) * w0.z;  wd[3] = bfhi(qd0.y) * w0.w;
    wd[4] = bflo(qd0.z) * w1.x;  wd[5] = bfhi(qd0.z) * w1.y;
    wd[6] = bflo(qd0.w) * w1.z;  wd[7] = bfhi(qd0.w) * w1.w;
    wd[8] = bflo(qd1.x) * w2.x;  wd[9] = bfhi(qd1.x) * w2.y;
    wd[10] = bflo(qd1.y) * w2.z; wd[11] = bfhi(qd1.y) * w2.w;
    wd[12] = bflo(qd1.z) * w3.x; wd[13] = bfhi(qd1.z) * w3.y;
    wd[14] = bflo(qd1.w) * w3.z; wd[15] = bfhi(qd1.w) * w3.w;
  }

  int r0 = rowptr[d], r1 = rowptr[d + 1];
  for (int r = r0; r < r1; r += 8) {
    int rr0 = r + g, rr1 = r + 4 + g;
    int s0 = 0, id0 = -1, s1 = 0, id1 = -1;
    if (rr0 < r1) { int2 p = ce[rr0]; s0 = p.x; id0 = p.y; }
    if (rr1 < r1) { int2 p = ce[rr1]; s1 = p.x; id1 = p.y; }
    const uint4* ra = (const uint4*)(h2b + (size_t)s0 * HC + l * 16);
    const uint4* rb = (const uint4*)(h2b + (size_t)s1 * HC + l * 16);
    uint4 a0 = ra[0], a1 = ra[1];
    uint4 c0 = rb[0], c1 = rb[1];
    float p0 = bflo(a0.x) * wd[0] + bfhi(a0.x) * wd[1] + bflo(a0.y) * wd[2] +
               bfhi(a0.y) * wd[3] + bflo(a0.z) * wd[4] + bfhi(a0.z) * wd[5] +
               bflo(a0.w) * wd[6] + bfhi(a0.w) * wd[7] + bflo(a1.x) * wd[8] +
               bfhi(a1.x) * wd[9] + bflo(a1.y) * wd[10] + bfhi(a1.y) * wd[11] +
               bflo(a1.z) * wd[12] + bfhi(a1.z) * wd[13] + bflo(a1.w) * wd[14] +
               bfhi(a1.w) * wd[15];
    float p1 = bflo(c0.x) * wd[0] + bfhi(c0.x) * wd[1] + bflo(c0.y) * wd[2] +
               bfhi(c0.y) * wd[3] + bflo(c0.z) * wd[4] + bfhi(c0.z) * wd[5] +
               bflo(c0.w) * wd[6] + bfhi(c0.w) * wd[7] + bflo(c1.x) * wd[8] +
               bfhi(c1.x) * wd[9] + bflo(c1.y) * wd[10] + bfhi(c1.y) * wd[11] +
               bflo(c1.z) * wd[12] + bfhi(c1.z) * wd[13] + bflo(c1.w) * wd[14] +
               bfhi(c1.w) * wd[15];
#pragma unroll
    for (int off = 1; off <= 8; off <<= 1) {
      p0 += __shfl_xor(p0, off);
      p1 += __shfl_xor(p1, off);
    }
    if (l == 0) {
      if (id0 >= 0) out[id0] = p0 + b;
      if (id1 >= 0) out[id1] = p1 + b;
    }
  }
}

extern "C" void kernel_launch(void* const* d_in, const int* in_sizes, int n_in,
                              void* d_out, int out_size, void* d_ws, size_t ws_size,
                              hipStream_t stream) {
  const float* x  = (const float*)d_in[0];
  const int* ei   = (const int*)d_in[1];
  const float* W1 = (const float*)d_in[3];
  const float* as1 = (const float*)d_in[4];
  const float* ad1 = (const float*)d_in[5];
  const float* b1 = (const float*)d_in[6];
  const float* W2 = (const float*)d_in[7];
  const float* as2 = (const float*)d_in[8];
  const float* ad2 = (const float*)d_in[9];
  const float* b2 = (const float*)d_in[10];
  const float* We = (const float*)d_in[11];
  const float* be = (const float*)d_in[12];
  const float* Wn = (const float*)d_in[13];
  const float* bn = (const float*)d_in[14];
  float* out = (float*)d_out;

  char* wsp = (char*)d_ws;
  auto alloc = [&](size_t bytes) {
    char* p = wsp;
    wsp += (bytes + 255) & ~(size_t)255;
    return p;
  };
  unsigned short* hbA = (unsigned short*)alloc((size_t)NN * HC * 2); // gemm out (both layers)
  unsigned short* h1b = (unsigned short*)alloc((size_t)NN * HC * 2); // agg1 out (xh aliases)
  unsigned short* hbB = (unsigned short*)alloc((size_t)NN * HC * 2); // agg2 out
  float* a_s = (float*)alloc((size_t)NN * 8 * 4);
  float* a_d = (float*)alloc((size_t)NN * 8 * 4);
  int* rowptr = (int*)alloc((size_t)(NN + 1) * 4);
  int2* ce = (int2*)alloc((size_t)(NE + NN + 8) * 8);  // (src, edge-id) pairs
  int* counts = (int*)alloc((size_t)NN * 4);
  int* tmp = (int*)alloc((size_t)NN * 4);
  int* scanbuf = (int*)alloc((size_t)NN * 4);
  int* bsum = (int*)alloc(256 * 4);
  int* boff = (int*)alloc(256 * 4);
  unsigned short* W1th = (unsigned short*)alloc((size_t)FIN * HC * 2);
  unsigned short* W1tl = (unsigned short*)alloc((size_t)FIN * HC * 2);
  unsigned short* W2th = (unsigned short*)alloc((size_t)HC * HC * 2);
  unsigned short* W2tl = (unsigned short*)alloc((size_t)HC * HC * 2);

  unsigned short* xh = h1b;  // x bf16 consumed by gemm1 before agg1 writes h1b

  const int NB = (NN + 255) / 256;

  // prep: zero counters + all dtype conversions (one launch)
  prep_kernel<<<NB_ZERO + NB_X + NB_W1 + NB_W2, 256, 0, stream>>>(
      x, xh, W1, W1th, W1tl, W2, W2th, W2tl, counts, tmp);
  // CSR build
  hist_kernel<<<(NE + 255) / 256, 256, 0, stream>>>(ei, counts);
  scan1<<<NB, 256, 0, stream>>>(counts, scanbuf, bsum);
  scan2<<<1, 256, 0, stream>>>(bsum, boff, NB);
  scan3<<<NB, 256, 0, stream>>>(scanbuf, boff, rowptr);

  // layer 1 gemm+coef, with CSR scatter fused into trailing blocks
  gemm_coef<<<GEMM_BLOCKS + NSB, 256, 0, stream>>>(
      xh, W1th, W1tl, as1, ad1, hbA, a_s, a_d, NN, FIN, ei, rowptr, tmp, ce);
  agg_kernel<<<NN / 8, 256, 0, stream>>>(hbA, a_s, a_d, rowptr, ce, b1, h1b,
                                         (const float*)nullptr, (const float*)nullptr,
                                         (float*)nullptr);

  // layer 2 (node_pred fused into agg epilogue)
  gemm_coef<<<GEMM_BLOCKS, 256, 0, stream>>>(
      h1b, W2th, W2tl, as2, ad2, hbA, a_s, a_d, NN, HC,
      (const int*)nullptr, rowptr, tmp, ce);
  agg_kernel<<<NN / 8, 256, 0, stream>>>(hbA, a_s, a_d, rowptr, ce, b2, hbB,
                                         Wn, bn, out + NE);

  // edge predictions
  edge_pred_kernel<<<NN / 4, 256, 0, stream>>>(hbB, rowptr, ce, We, be, out);
}

// Round 12
// 435.659 us; speedup vs baseline: 2.0040x; 1.0243x over previous
//
#include <hip/hip_runtime.h>
#include <hip/hip_bf16.h>

#define NN 50000
#define NE 800000
#define FIN 128
#define HC 256
#define NEG_SLOPE 0.2f

#define GEMM_BLOCKS 1564  // ceil(NN/64)*2  (64x128 tiles)
#define NSB 3321          // ceil((NE+NN)/256) scatter blocks
#define NB_ZERO 196       // ceil(NN/256)
#define NB_X 6250         // NN*FIN/4/256
#define NB_W1 128         // FIN*HC/256
#define NB_W2 256         // HC*HC/256

typedef short bf16x8 __attribute__((ext_vector_type(8)));
typedef float f32x4 __attribute__((ext_vector_type(4)));

__device__ __forceinline__ unsigned short f2bf(float f) {
  unsigned u = __float_as_uint(f);
  u += 0x7fff + ((u >> 16) & 1);  // RTN-even
  return (unsigned short)(u >> 16);
}
__device__ __forceinline__ float bf2f(unsigned short s) {
  return __uint_as_float((unsigned)s << 16);
}
__device__ __forceinline__ float bflo(unsigned u) { return __uint_as_float(u << 16); }
__device__ __forceinline__ float bfhi(unsigned u) { return __uint_as_float(u & 0xffff0000u); }

// ---------------- fused prep: zero counts/tmp + convert x + transpose/split W1,W2 ----
__global__ __launch_bounds__(256) void prep_kernel(
    const float* __restrict__ X, unsigned short* __restrict__ Xh,
    const float* __restrict__ W1, unsigned short* __restrict__ W1th,
    unsigned short* __restrict__ W1tl, const float* __restrict__ W2,
    unsigned short* __restrict__ W2th, unsigned short* __restrict__ W2tl,
    int* __restrict__ counts, int* __restrict__ tmp) {
  int b = blockIdx.x, t = threadIdx.x;
  if (b < NB_ZERO) {
    int i = b * 256 + t;
    if (i < NN) { counts[i] = 0; tmp[i] = 0; }
  } else if (b < NB_ZERO + NB_X) {
    int i = (b - NB_ZERO) * 256 + t;  // exact: NN*FIN/4 = 1.6M
    float4 v = ((const float4*)X)[i];
    ushort4 h;
    h.x = f2bf(v.x); h.y = f2bf(v.y); h.z = f2bf(v.z); h.w = f2bf(v.w);
    ((ushort4*)Xh)[i] = h;
  } else if (b < NB_ZERO + NB_X + NB_W1) {
    int j = (b - NB_ZERO - NB_X) * 256 + t;  // j = n*K+k, output-contiguous, K=128
    int n = j >> 7, k = j & 127;
    float v = W1[k * HC + n];
    unsigned short h = f2bf(v);
    W1th[j] = h;
    W1tl[j] = f2bf(v - bf2f(h));
  } else {
    int j = (b - NB_ZERO - NB_X - NB_W1) * 256 + t;  // K=256
    int n = j >> 8, k = j & 255;
    float v = W2[k * HC + n];
    unsigned short h = f2bf(v);
    W2th[j] = h;
    W2tl[j] = f2bf(v - bf2f(h));
  }
}

// ---------------- MFMA GEMM + fused coef, 64x128 tile ----------------
// Cb(bf16) = A_bf16 @ (Bh+Bl)^T(stored [N][K]); 2-term split.
// 64x128 tile, 4 waves (each 32x64): grid 1564 = 6.1 blocks/CU (round-11's 128x128
// gave 782 = 3.05/CU -> latency/tail-bound, MfmaUtil 3%, Occupancy 27%).
// Coef: 16-lane shuffle reduce -> LDS -> one float4/row store (round-11's scattered
// 4B coef stores amplified WRITE_SIZE to 85MB; round-8's contiguous stores showed 31MB).
// C stored as quad-contiguous 2B scalars (32B sectors; round-10's 16B/512B-stride
// uint4 stores amplified writes 3x — do not repeat).
// Trailing blocks (layer-1 launch) run the CSR scatter — independent work.
__global__ __launch_bounds__(256) void gemm_coef(
    const unsigned short* __restrict__ A, const unsigned short* __restrict__ Bth,
    const unsigned short* __restrict__ Btl, const float* __restrict__ att_s,
    const float* __restrict__ att_d, unsigned short* __restrict__ Cb,
    float* __restrict__ a_s, float* __restrict__ a_d, int M, int K,
    const int* __restrict__ ei, const int* __restrict__ rowptr,
    int* __restrict__ tmpc, int2* __restrict__ ce) {
  __shared__ unsigned short sA[64 * 40];    // stride 40 shorts: <=2-way banks (free)
  __shared__ unsigned short sBh[128 * 40];
  __shared__ unsigned short sBl[128 * 40];
  __shared__ float sCS[64][4];
  __shared__ float sCD[64][4];

  int bid = blockIdx.x, t = threadIdx.x;
  if (bid >= GEMM_BLOCKS) {
    // fused scatter path (layer-1 launch only)
    int e = (bid - GEMM_BLOCKS) * 256 + t;
    if (e < NE + NN) {
      int s, d, id;
      if (e < NE) { s = ei[e]; d = ei[NE + e]; id = e; }
      else { s = d = e - NE; id = -1; }
      int pos = rowptr[d] + atomicAdd(&tmpc[d], 1);
      ce[pos] = make_int2(s, id);
    }
    return;
  }

  int w = t >> 6, lane = t & 63;
  int quad = lane >> 4, lrow = lane & 15;
  int m0 = (bid >> 1) * 64, n0 = (bid & 1) * 128;
  int rm = (w & 1) * 32, cn = (w >> 1) * 64;

  f32x4 acc[2][4] = {};

  for (int k0 = 0; k0 < K; k0 += 32) {
    // stage A: 64 rows x 4 chunks = 256 -> 1/thread
    {
      int row = t >> 2, q = t & 3;
      int gm = m0 + row;
      if (gm >= M) gm = M - 1;
      *(uint4*)(sA + row * 40 + q * 8) = *(const uint4*)(A + (size_t)gm * K + k0 + q * 8);
    }
    // stage B: 128 rows x 4 chunks = 512 -> 2/thread
#pragma unroll
    for (int i = 0; i < 2; ++i) {
      int idx = t + i * 256;
      int row = idx >> 2, q = idx & 3;
      size_t gb = (size_t)(n0 + row) * K + k0 + q * 8;
      *(uint4*)(sBh + row * 40 + q * 8) = *(const uint4*)(Bth + gb);
      *(uint4*)(sBl + row * 40 + q * 8) = *(const uint4*)(Btl + gb);
    }
    __syncthreads();

    bf16x8 fa[2];
#pragma unroll
    for (int mi = 0; mi < 2; ++mi)
      fa[mi] = *(const bf16x8*)(sA + (rm + mi * 16 + lrow) * 40 + quad * 8);
#pragma unroll
    for (int ni = 0; ni < 4; ++ni) {
      bf16x8 fbh = *(const bf16x8*)(sBh + (cn + ni * 16 + lrow) * 40 + quad * 8);
      bf16x8 fbl = *(const bf16x8*)(sBl + (cn + ni * 16 + lrow) * 40 + quad * 8);
#pragma unroll
      for (int mi = 0; mi < 2; ++mi) {
        acc[mi][ni] = __builtin_amdgcn_mfma_f32_16x16x32_bf16(fa[mi], fbh, acc[mi][ni], 0, 0, 0);
        acc[mi][ni] = __builtin_amdgcn_mfma_f32_16x16x32_bf16(fa[mi], fbl, acc[mi][ni], 0, 0, 0);
      }
    }
    __syncthreads();
  }

  // att values for this lane's 4 columns (hoisted)
  float vs[4], vd[4];
#pragma unroll
  for (int ni = 0; ni < 4; ++ni) {
    int gn = n0 + cn + ni * 16 + lrow;
    vs[ni] = att_s[gn];
    vd[ni] = att_d[gn];
  }
  int h4e = cn >> 5;  // local head pair base: 0 (cols 0-63) or 2 (cols 64-127)

  // C/D layout: col = lane&15, row = quad*4 + reg  [m89-verified]
#pragma unroll
  for (int mi = 0; mi < 2; ++mi) {
#pragma unroll
    for (int r = 0; r < 4; ++r) {
      int lr = rm + mi * 16 + quad * 4 + r;  // local row 0..63
      int gm = m0 + lr;
      if (gm < M) {
#pragma unroll
        for (int ni = 0; ni < 4; ++ni) {
          int gn = n0 + cn + ni * 16 + lrow;
          Cb[(size_t)gm * HC + gn] = f2bf(acc[mi][ni][r]);
        }
      }
      // per-head partial dots: ni 0,1 -> local head h4e ; ni 2,3 -> h4e+1
      float pse = acc[mi][0][r] * vs[0] + acc[mi][1][r] * vs[1];
      float pso = acc[mi][2][r] * vs[2] + acc[mi][3][r] * vs[3];
      float pde = acc[mi][0][r] * vd[0] + acc[mi][1][r] * vd[1];
      float pdo = acc[mi][2][r] * vd[2] + acc[mi][3][r] * vd[3];
#pragma unroll
      for (int off = 1; off <= 8; off <<= 1) {
        pse += __shfl_xor(pse, off);
        pso += __shfl_xor(pso, off);
        pde += __shfl_xor(pde, off);
        pdo += __shfl_xor(pdo, off);
      }
      if (lrow == 0) {
        sCS[lr][h4e] = pse;
        sCS[lr][h4e + 1] = pso;
        sCD[lr][h4e] = pde;
        sCD[lr][h4e + 1] = pdo;
      }
    }
  }
  __syncthreads();
  // contiguous 16B coef writeback (one float4 per row per array)
  if (t < 64) {
    int gm = m0 + t;
    if (gm < M) {
      int o = (n0 >> 5);  // 0 or 4
      *(float4*)(a_s + (size_t)gm * 8 + o) = *(const float4*)&sCS[t][0];
      *(float4*)(a_d + (size_t)gm * 8 + o) = *(const float4*)&sCD[t][0];
    }
  }
}

// ---------------- CSR build ----------------
__global__ void hist_kernel(const int* __restrict__ ei, int* __restrict__ counts) {
  int e = blockIdx.x * 256 + threadIdx.x;
  if (e < NE) atomicAdd(&counts[ei[NE + e]], 1);
}

__global__ void scan1(const int* __restrict__ counts, int* __restrict__ scanbuf,
                      int* __restrict__ bsum) {
  __shared__ int sd[256];
  int t = threadIdx.x;
  int i = blockIdx.x * 256 + t;
  int v = (i < NN) ? counts[i] + 1 : 0;  // +1 = self-loop
  sd[t] = v;
  __syncthreads();
#pragma unroll
  for (int off = 1; off < 256; off <<= 1) {
    int x = (t >= off) ? sd[t - off] : 0;
    __syncthreads();
    sd[t] += x;
    __syncthreads();
  }
  if (i < NN) scanbuf[i] = sd[t];
  if (t == 255) bsum[blockIdx.x] = sd[255];
}

__global__ void scan2(const int* __restrict__ bsum, int* __restrict__ boff, int nb) {
  __shared__ int sd[256];
  int t = threadIdx.x;
  int v = (t < nb) ? bsum[t] : 0;
  sd[t] = v;
  __syncthreads();
#pragma unroll
  for (int off = 1; off < 256; off <<= 1) {
    int x = (t >= off) ? sd[t - off] : 0;
    __syncthreads();
    sd[t] += x;
    __syncthreads();
  }
  if (t < nb) boff[t] = sd[t] - v;  // exclusive
}

__global__ void scan3(const int* __restrict__ scanbuf, const int* __restrict__ boff,
                      int* __restrict__ rowptr) {
  int i = blockIdx.x * 256 + threadIdx.x;
  if (i < NN) rowptr[i + 1] = scanbuf[i] + boff[blockIdx.x];
  if (i == 0) rowptr[0] = 0;
}

// ---------------- aggregation: 32 lanes/dst, masked 4-edge unroll, no-max softmax ----
__global__ __launch_bounds__(256) void agg_kernel(
    const unsigned short* __restrict__ htb, const float* __restrict__ a_s,
    const float* __restrict__ a_d, const int* __restrict__ rowptr,
    const int2* __restrict__ ce, const float* __restrict__ bias,
    unsigned short* __restrict__ outb,
    const float* __restrict__ Wn, const float* __restrict__ bn,
    float* __restrict__ outn) {
  int d = blockIdx.x * 8 + (threadIdx.x >> 5);
  if (d >= NN) return;
  int l = threadIdx.x & 31;
  int hh = l >> 2;
  float adh = a_d[d * 8 + hh];
  int r0 = rowptr[d], r1 = rowptr[d + 1];
  float denom = 0.f;
  float4 acc0 = {0.f, 0.f, 0.f, 0.f};
  float4 acc1 = {0.f, 0.f, 0.f, 0.f};
  for (int r = r0; r < r1; r += 4) {
    int s[4];
    float as_[4];
    uint4 q[4];
    bool ok[4];
#pragma unroll
    for (int j = 0; j < 4; ++j) {
      int rj = r + j;
      ok[j] = rj < r1;
      rj = ok[j] ? rj : r1 - 1;  // clamp: duplicate load, weight zeroed
      s[j] = ce[rj].x;
    }
#pragma unroll
    for (int j = 0; j < 4; ++j) {
      as_[j] = a_s[s[j] * 8 + hh];
      q[j] = ((const uint4*)(htb + (size_t)s[j] * HC))[l];
    }
#pragma unroll
    for (int j = 0; j < 4; ++j) {
      float e = as_[j] + adh;
      e = e > 0.f ? e : NEG_SLOPE * e;
      float w = ok[j] ? __expf(e) : 0.f;
      denom += w;
      acc0.x += w * bflo(q[j].x);
      acc0.y += w * bfhi(q[j].x);
      acc0.z += w * bflo(q[j].y);
      acc0.w += w * bfhi(q[j].y);
      acc1.x += w * bflo(q[j].z);
      acc1.y += w * bfhi(q[j].z);
      acc1.z += w * bflo(q[j].w);
      acc1.w += w * bfhi(q[j].w);
    }
  }
  float dv = 1.f / denom;  // denom >= 1 (self-loop)
  float4 b0 = *(const float4*)(bias + l * 8);
  float4 b1 = *(const float4*)(bias + l * 8 + 4);
  float4 o0, o1;
  o0.x = fmaxf(fmaf(acc0.x, dv, b0.x), 0.f);
  o0.y = fmaxf(fmaf(acc0.y, dv, b0.y), 0.f);
  o0.z = fmaxf(fmaf(acc0.z, dv, b0.z), 0.f);
  o0.w = fmaxf(fmaf(acc0.w, dv, b0.w), 0.f);
  o1.x = fmaxf(fmaf(acc1.x, dv, b1.x), 0.f);
  o1.y = fmaxf(fmaf(acc1.y, dv, b1.y), 0.f);
  o1.z = fmaxf(fmaf(acc1.z, dv, b1.z), 0.f);
  o1.w = fmaxf(fmaf(acc1.w, dv, b1.w), 0.f);
  uint4 pb;
  pb.x = (unsigned)f2bf(o0.x) | ((unsigned)f2bf(o0.y) << 16);
  pb.y = (unsigned)f2bf(o0.z) | ((unsigned)f2bf(o0.w) << 16);
  pb.z = (unsigned)f2bf(o1.x) | ((unsigned)f2bf(o1.y) << 16);
  pb.w = (unsigned)f2bf(o1.z) | ((unsigned)f2bf(o1.w) << 16);
  ((uint4*)(outb + (size_t)d * HC))[l] = pb;
  if (outn) {
    const float4* wnp = (const float4*)(Wn + l * 8);
    float4 w0 = wnp[0], w1 = wnp[1];
    float p = o0.x * w0.x + o0.y * w0.y + o0.z * w0.z + o0.w * w0.w +
              o1.x * w1.x + o1.y * w1.y + o1.z * w1.z + o1.w * w1.w;
#pragma unroll
    for (int off = 1; off <= 16; off <<= 1) p += __shfl_xor(p, off);
    if (l == 0) outn[d] = p + bn[0];
  }
}

// ---------------- edge predictions: 16-lane group per edge, 2-edge unroll ----------------
__global__ __launch_bounds__(256) void edge_pred_kernel(
    const unsigned short* __restrict__ h2b, const int* __restrict__ rowptr,
    const int2* __restrict__ ce, const float* __restrict__ We,
    const float* __restrict__ be, float* __restrict__ out) {
  int d = blockIdx.x * 4 + (threadIdx.x >> 6);
  if (d >= NN) return;
  int lane = threadIdx.x & 63;
  int g = lane >> 4, l = lane & 15;
  float b = be[0];

  const uint4* rowd = (const uint4*)(h2b + (size_t)d * HC + l * 16);
  uint4 qd0 = rowd[0], qd1 = rowd[1];
  float wd[16];
  {
    const float4* wep = (const float4*)(We + l * 16);
    float4 w0 = wep[0], w1 = wep[1], w2 = wep[2], w3 = wep[3];
    wd[0] = bflo(qd0.x) * w0.x;  wd[1] = bfhi(qd0.x) * w0.y;
    wd[2] = bflo(qd0.y) * w0.z;  wd[3] = bfhi(qd0.y) * w0.w;
    wd[4] = bflo(qd0.z) * w1.x;  wd[5] = bfhi(qd0.z) * w1.y;
    wd[6] = bflo(qd0.w) * w1.z;  wd[7] = bfhi(qd0.w) * w1.w;
    wd[8] = bflo(qd1.x) * w2.x;  wd[9] = bfhi(qd1.x) * w2.y;
    wd[10] = bflo(qd1.y) * w2.z; wd[11] = bfhi(qd1.y) * w2.w;
    wd[12] = bflo(qd1.z) * w3.x; wd[13] = bfhi(qd1.z) * w3.y;
    wd[14] = bflo(qd1.w) * w3.z; wd[15] = bfhi(qd1.w) * w3.w;
  }

  int r0 = rowptr[d], r1 = rowptr[d + 1];
  for (int r = r0; r < r1; r += 8) {
    int rr0 = r + g, rr1 = r + 4 + g;
    int s0 = 0, id0 = -1, s1 = 0, id1 = -1;
    if (rr0 < r1) { int2 p = ce[rr0]; s0 = p.x; id0 = p.y; }
    if (rr1 < r1) { int2 p = ce[rr1]; s1 = p.x; id1 = p.y; }
    const uint4* ra = (const uint4*)(h2b + (size_t)s0 * HC + l * 16);
    const uint4* rb = (const uint4*)(h2b + (size_t)s1 * HC + l * 16);
    uint4 a0 = ra[0], a1 = ra[1];
    uint4 c0 = rb[0], c1 = rb[1];
    float p0 = bflo(a0.x) * wd[0] + bfhi(a0.x) * wd[1] + bflo(a0.y) * wd[2] +
               bfhi(a0.y) * wd[3] + bflo(a0.z) * wd[4] + bfhi(a0.z) * wd[5] +
               bflo(a0.w) * wd[6] + bfhi(a0.w) * wd[7] + bflo(a1.x) * wd[8] +
               bfhi(a1.x) * wd[9] + bflo(a1.y) * wd[10] + bfhi(a1.y) * wd[11] +
               bflo(a1.z) * wd[12] + bfhi(a1.z) * wd[13] + bflo(a1.w) * wd[14] +
               bfhi(a1.w) * wd[15];
    float p1 = bflo(c0.x) * wd[0] + bfhi(c0.x) * wd[1] + bflo(c0.y) * wd[2] +
               bfhi(c0.y) * wd[3] + bflo(c0.z) * wd[4] + bfhi(c0.z) * wd[5] +
               bflo(c0.w) * wd[6] + bfhi(c0.w) * wd[7] + bflo(c1.x) * wd[8] +
               bfhi(c1.x) * wd[9] + bflo(c1.y) * wd[10] + bfhi(c1.y) * wd[11] +
               bflo(c1.z) * wd[12] + bfhi(c1.z) * wd[13] + bflo(c1.w) * wd[14] +
               bfhi(c1.w) * wd[15];
#pragma unroll
    for (int off = 1; off <= 8; off <<= 1) {
      p0 += __shfl_xor(p0, off);
      p1 += __shfl_xor(p1, off);
    }
    if (l == 0) {
      if (id0 >= 0) out[id0] = p0 + b;
      if (id1 >= 0) out[id1] = p1 + b;
    }
  }
}

extern "C" void kernel_launch(void* const* d_in, const int* in_sizes, int n_in,
                              void* d_out, int out_size, void* d_ws, size_t ws_size,
                              hipStream_t stream) {
  const float* x  = (const float*)d_in[0];
  const int* ei   = (const int*)d_in[1];
  const float* W1 = (const float*)d_in[3];
  const float* as1 = (const float*)d_in[4];
  const float* ad1 = (const float*)d_in[5];
  const float* b1 = (const float*)d_in[6];
  const float* W2 = (const float*)d_in[7];
  const float* as2 = (const float*)d_in[8];
  const float* ad2 = (const float*)d_in[9];
  const float* b2 = (const float*)d_in[10];
  const float* We = (const float*)d_in[11];
  const float* be = (const float*)d_in[12];
  const float* Wn = (const float*)d_in[13];
  const float* bn = (const float*)d_in[14];
  float* out = (float*)d_out;

  char* wsp = (char*)d_ws;
  auto alloc = [&](size_t bytes) {
    char* p = wsp;
    wsp += (bytes + 255) & ~(size_t)255;
    return p;
  };
  unsigned short* hbA = (unsigned short*)alloc((size_t)NN * HC * 2); // gemm out (both layers)
  unsigned short* h1b = (unsigned short*)alloc((size_t)NN * HC * 2); // agg1 out (xh aliases)
  unsigned short* hbB = (unsigned short*)alloc((size_t)NN * HC * 2); // agg2 out
  float* a_s = (float*)alloc((size_t)NN * 8 * 4);
  float* a_d = (float*)alloc((size_t)NN * 8 * 4);
  int* rowptr = (int*)alloc((size_t)(NN + 1) * 4);
  int2* ce = (int2*)alloc((size_t)(NE + NN + 8) * 8);  // (src, edge-id) pairs
  int* counts = (int*)alloc((size_t)NN * 4);
  int* tmp = (int*)alloc((size_t)NN * 4);
  int* scanbuf = (int*)alloc((size_t)NN * 4);
  int* bsum = (int*)alloc(256 * 4);
  int* boff = (int*)alloc(256 * 4);
  unsigned short* W1th = (unsigned short*)alloc((size_t)FIN * HC * 2);
  unsigned short* W1tl = (unsigned short*)alloc((size_t)FIN * HC * 2);
  unsigned short* W2th = (unsigned short*)alloc((size_t)HC * HC * 2);
  unsigned short* W2tl = (unsigned short*)alloc((size_t)HC * HC * 2);

  unsigned short* xh = h1b;  // x bf16 consumed by gemm1 before agg1 writes h1b

  const int NB = (NN + 255) / 256;

  // prep: zero counters + all dtype conversions (one launch)
  prep_kernel<<<NB_ZERO + NB_X + NB_W1 + NB_W2, 256, 0, stream>>>(
      x, xh, W1, W1th, W1tl, W2, W2th, W2tl, counts, tmp);
  // CSR build
  hist_kernel<<<(NE + 255) / 256, 256, 0, stream>>>(ei, counts);
  scan1<<<NB, 256, 0, stream>>>(counts, scanbuf, bsum);
  scan2<<<1, 256, 0, stream>>>(bsum, boff, NB);
  scan3<<<NB, 256, 0, stream>>>(scanbuf, boff, rowptr);

  // layer 1 gemm+coef, with CSR scatter fused into trailing blocks
  gemm_coef<<<GEMM_BLOCKS + NSB, 256, 0, stream>>>(
      xh, W1th, W1tl, as1, ad1, hbA, a_s, a_d, NN, FIN, ei, rowptr, tmp, ce);
  agg_kernel<<<NN / 8, 256, 0, stream>>>(hbA, a_s, a_d, rowptr, ce, b1, h1b,
                                         (const float*)nullptr, (const float*)nullptr,
                                         (float*)nullptr);

  // layer 2 (node_pred fused into agg epilogue)
  gemm_coef<<<GEMM_BLOCKS, 256, 0, stream>>>(
      h1b, W2th, W2tl, as2, ad2, hbA, a_s, a_d, NN, HC,
      (const int*)nullptr, rowptr, tmp, ce);
  agg_kernel<<<NN / 8, 256, 0, stream>>>(hbA, a_s, a_d, rowptr, ce, b2, hbB,
                                         Wn, bn, out + NE);

  // edge predictions
  edge_pred_kernel<<<NN / 4, 256, 0, stream>>>(hbB, rowptr, ce, We, be, out);
}